// Round 11
// baseline (848.415 us; speedup 1.0000x reference)
//
#include <hip/hip_runtime.h>
#include <hip/hip_bf16.h>

typedef unsigned short ushort_t;
typedef __attribute__((ext_vector_type(8))) short bf16x8;
typedef __attribute__((ext_vector_type(4))) short bf16x4;
typedef __attribute__((ext_vector_type(4))) float f32x4;
typedef __attribute__((ext_vector_type(4))) unsigned short u16x4;
typedef __attribute__((ext_vector_type(4))) unsigned int u32x4;

#define DEV __device__ __forceinline__

// ---------- helpers ----------
DEV ushort_t f2bf(float f) {
  __hip_bfloat16 h = __float2bfloat16(f);   // hardware RNE convert
  return __builtin_bit_cast(unsigned short, h);
}
DEV float bf2f(ushort_t b) {
  union { float f; unsigned int u; } a; a.u = ((unsigned int)b) << 16;
  return a.f;
}
DEV void gload_lds16(const void* g, void* l) {
  __builtin_amdgcn_global_load_lds((const __attribute__((address_space(1))) void*)g,
                                   (__attribute__((address_space(3))) void*)l, 16, 0, 0);
}
DEV unsigned ldsaddr(const void* l) {
  return (unsigned)(unsigned long long)(const __attribute__((address_space(3))) void*)l;
}
template <int OFF>
DEV bf16x4 tr16o(unsigned a) {
  bf16x4 d;
  asm volatile("ds_read_b64_tr_b16 %0, %1 offset:%c2" : "=v"(d) : "v"(a), "i"(OFF));
  return d;
}
template <int OFF>
DEV bf16x8 ldsb128o(unsigned a) {
  bf16x8 d;
  asm volatile("ds_read_b128 %0, %1 offset:%c2" : "=v"(d) : "v"(a), "i"(OFF));
  return d;
}

// ---------- f32 -> bf16 convert ----------
__global__ __launch_bounds__(256) void f2b_kernel(const float* __restrict__ in,
                                                  ushort_t* __restrict__ out, int n) {
  int base = (blockIdx.x * 256 + threadIdx.x) * 4;
  if (base >= n) return;
  f32x4 v = *(const f32x4*)(in + base);
  u16x4 o;
  o.x = f2bf(v.x); o.y = f2bf(v.y); o.z = f2bf(v.z); o.w = f2bf(v.w);
  *(u16x4*)(out + base) = o;
}

// fused 3-tensor convert (per-layer wq/wk/wv), each 4194304 elements
__global__ __launch_bounds__(256) void f2b3_kernel(const float* __restrict__ a, const float* __restrict__ b,
                                                   const float* __restrict__ c, ushort_t* __restrict__ out) {
  int id = blockIdx.x * 256 + threadIdx.x;
  int sel = id >> 20, k = (id & 1048575) * 4;
  const float* src = sel == 0 ? a : sel == 1 ? b : c;
  f32x4 v = *(const f32x4*)(src + k);
  u16x4 o;
  o.x = f2bf(v.x); o.y = f2bf(v.y); o.z = f2bf(v.z); o.w = f2bf(v.w);
  *(u16x4*)(out + (size_t)sel * 4194304 + k) = o;
}

// ---------- lambda weights ----------
__global__ void lam_kernel(const float* __restrict__ lambdas, float* __restrict__ lam) {
  if (threadIdx.x == 0 && blockIdx.x == 0) {
    float l0 = 1.f / (1.f + __expf(-lambdas[0]));
    float l1 = 1.f / (1.f + __expf(-lambdas[1]));
    float l2 = 1.f / (1.f + __expf(-lambdas[2]));
    float mean = (l0 + l1 + l2) * (1.f / 3.f);
    float d0 = l0 - mean, d1 = l1 - mean, d2 = l2 - mean;
    float var = (d0 * d0 + d1 * d1 + d2 * d2) * (1.f / 3.f);
    float rs = rsqrtf(var + 1e-5f);
    lam[0] = d0 * rs; lam[1] = d1 * rs; lam[2] = d2 * rs;
  }
}

// ---------- legacy 128x128 GEMM core (used by final projection) ----------
DEV void gemm_core(const ushort_t* __restrict__ A, const ushort_t* __restrict__ Bm,
                   ushort_t* lsA, ushort_t* lsB, int bm, int bn, int kbeg, int kend,
                   f32x4 (&acc)[4][4]) {
  const int K = 2048;
  int tid = threadIdx.x;
  int w = tid >> 6, lane = tid & 63;
  int g = lane >> 4, r = lane & 15;
  int wm = w >> 1, wn = w & 1;
#pragma unroll
  for (int i = 0; i < 4; ++i)
#pragma unroll
    for (int j = 0; j < 4; ++j) acc[i][j] = 0.f;

  for (int kk = kbeg; kk < kend; kk += 32) {
    __syncthreads();
#pragma unroll
    for (int j2 = 0; j2 < 2; ++j2) {
      int eb = w * 1024 + j2 * 512;
      int ebl = eb + lane * 8;
      int rr = ebl >> 5, cc = ebl & 31;
      gload_lds16(A + (size_t)(bm * 128 + rr) * K + kk + cc, lsA + eb);
      gload_lds16(Bm + (size_t)(bn * 128 + rr) * K + kk + cc, lsB + eb);
    }
    __syncthreads();
    bf16x8 af[4], bfr[4];
#pragma unroll
    for (int i = 0; i < 4; ++i)
      af[i] = *(const bf16x8*)(lsA + (wm * 64 + i * 16 + r) * 32 + g * 8);
#pragma unroll
    for (int j = 0; j < 4; ++j)
      bfr[j] = *(const bf16x8*)(lsB + (wn * 64 + j * 16 + r) * 32 + g * 8);
#pragma unroll
    for (int i = 0; i < 4; ++i)
#pragma unroll
      for (int j = 0; j < 4; ++j)
        acc[i][j] = __builtin_amdgcn_mfma_f32_16x16x32_bf16(af[i], bfr[j], acc[i][j], 0, 0, 0);
  }
}

// ---------- 8-phase 256x256 fused QKV GEMM (proven round 10) ----------
#define MM(i, j)                                                                              \
  acc[i][j] = __builtin_amdgcn_mfma_f32_16x16x32_bf16(af[(i) & 3][0], bfr[j][0], acc[i][j], 0, 0, 0); \
  acc[i][j] = __builtin_amdgcn_mfma_f32_16x16x32_bf16(af[(i) & 3][1], bfr[j][1], acc[i][j], 0, 0, 0);

__global__ __launch_bounds__(512, 2) void gemm_qkv256(
    const ushort_t* __restrict__ A,
    const ushort_t* __restrict__ Bq, const ushort_t* __restrict__ Bk, const ushort_t* __restrict__ Bv,
    ushort_t* __restrict__ Cq, ushort_t* __restrict__ Ck, ushort_t* __restrict__ Cv, int Lkv) {
  __shared__ __align__(16) ushort_t lsA[32768];
  __shared__ __align__(16) ushort_t lsB[32768];
  const int NT = 32;

  int bid = (int)blockIdx.x;
  int swz = (bid & 7) * 24 + (bid >> 3);
  int bm = swz / 24;
  int rest = swz % 24;
  int sel = rest >> 3, bnc = rest & 7;
  const ushort_t* Bmat = (sel == 0) ? Bq : (sel == 1) ? Bk : Bv;
  ushort_t* C = (sel == 0) ? Cq : (sel == 1) ? Ck : Cv;
  int Lsel = (sel == 0) ? 1024 : Lkv;

  int tid = threadIdx.x;
  int wv = tid >> 6, lane = tid & 63;
  int wm = wv >> 2, wn = wv & 3;
  int g = lane >> 4, r = lane & 15;

  int row0 = tid >> 3, c0 = tid & 7;
  int colsw = (c0 ^ (row0 & 7)) * 8;
  const ushort_t* pA0 = A + (size_t)(bm * 256 + row0) * 2048 + colsw;
  const ushort_t* pB0 = Bmat + (size_t)(bnc * 256 + row0) * 2048 + colsw;
  ushort_t* dA = lsA + tid * 8;
  ushort_t* dB = lsB + tid * 8;

  auto SA = [&](int T, int hh) {
    const ushort_t* s = pA0 + (size_t)(hh * 128) * 2048 + (size_t)T * 64;
    ushort_t* d = dA + (T & 1) * 16384 + hh * 8192;
    gload_lds16(s, d);
    gload_lds16(s + (size_t)64 * 2048, d + 4096);
  };
  auto SB = [&](int T, int hh) {
    const ushort_t* s = pB0 + (size_t)(hh * 128) * 2048 + (size_t)T * 64;
    ushort_t* d = dB + (T & 1) * 16384 + hh * 8192;
    gload_lds16(s, d);
    gload_lds16(s + (size_t)64 * 2048, d + 4096);
  };

  unsigned xm = (unsigned)(r & 7);
  unsigned aAb = ldsaddr(lsA) + (unsigned)((wm * 128 + r) * 128);
  unsigned aA0b = aAb + ((((unsigned)g) ^ xm) << 4);
  unsigned aA1b = aAb + ((((unsigned)(4 + g)) ^ xm) << 4);
  unsigned aBb = ldsaddr(lsB) + (unsigned)((wn * 64 + r) * 128);
  unsigned aB0b = aBb + ((((unsigned)g) ^ xm) << 4);
  unsigned aB1b = aBb + ((((unsigned)(4 + g)) ^ xm) << 4);

  f32x4 acc[8][4];
#pragma unroll
  for (int i = 0; i < 8; ++i)
#pragma unroll
    for (int j = 0; j < 4; ++j) acc[i][j] = 0.f;
  bf16x8 af[4][2], bfr[4][2];

  SA(0, 0); SB(0, 0); SB(0, 1); SA(0, 1);
  SA(1, 0); SB(1, 0); SB(1, 1);
  asm volatile("s_waitcnt vmcnt(6)" ::: "memory");
  __builtin_amdgcn_s_barrier();
  __builtin_amdgcn_sched_barrier(0);

  for (int t = 0; t < NT; ++t) {
    unsigned cb = (unsigned)((t & 1) << 15);
    unsigned A0 = aA0b + cb, A1 = aA1b + cb, B0 = aB0b + cb, B1 = aB1b + cb;
    bool full = (t < NT - 2);
    // phase 0
    af[0][0] = ldsb128o<0>(A0);     af[0][1] = ldsb128o<0>(A1);
    af[1][0] = ldsb128o<2048>(A0);  af[1][1] = ldsb128o<2048>(A1);
    af[2][0] = ldsb128o<4096>(A0);  af[2][1] = ldsb128o<4096>(A1);
    af[3][0] = ldsb128o<6144>(A0);  af[3][1] = ldsb128o<6144>(A1);
    bfr[0][0] = ldsb128o<0>(B0);    bfr[0][1] = ldsb128o<0>(B1);
    bfr[1][0] = ldsb128o<2048>(B0); bfr[1][1] = ldsb128o<2048>(B1);
    if (t + 1 < NT) SA(t + 1, 1);
    __builtin_amdgcn_s_barrier();
    asm volatile("s_waitcnt lgkmcnt(0)" ::: "memory");
    __builtin_amdgcn_sched_barrier(0);
    __builtin_amdgcn_s_setprio(1);
    MM(0, 0) MM(1, 0) MM(2, 0) MM(3, 0) MM(0, 1) MM(1, 1) MM(2, 1) MM(3, 1)
    __builtin_amdgcn_s_setprio(0);
    __builtin_amdgcn_sched_barrier(0);
    __builtin_amdgcn_s_barrier();
    // phase 1
    bfr[2][0] = ldsb128o<4096>(B0); bfr[2][1] = ldsb128o<4096>(B1);
    bfr[3][0] = ldsb128o<6144>(B0); bfr[3][1] = ldsb128o<6144>(B1);
    if (full) SA(t + 2, 0);
    __builtin_amdgcn_s_barrier();
    asm volatile("s_waitcnt lgkmcnt(0)" ::: "memory");
    __builtin_amdgcn_sched_barrier(0);
    __builtin_amdgcn_s_setprio(1);
    MM(0, 2) MM(1, 2) MM(2, 2) MM(3, 2) MM(0, 3) MM(1, 3) MM(2, 3) MM(3, 3)
    __builtin_amdgcn_s_setprio(0);
    if (full) { asm volatile("s_waitcnt vmcnt(4)" ::: "memory"); }
    else      { asm volatile("s_waitcnt vmcnt(0)" ::: "memory"); }
    __builtin_amdgcn_sched_barrier(0);
    __builtin_amdgcn_s_barrier();
    // phase 2
    af[0][0] = ldsb128o<8192>(A0);  af[0][1] = ldsb128o<8192>(A1);
    af[1][0] = ldsb128o<10240>(A0); af[1][1] = ldsb128o<10240>(A1);
    af[2][0] = ldsb128o<12288>(A0); af[2][1] = ldsb128o<12288>(A1);
    af[3][0] = ldsb128o<14336>(A0); af[3][1] = ldsb128o<14336>(A1);
    if (full) SB(t + 2, 0);
    __builtin_amdgcn_s_barrier();
    asm volatile("s_waitcnt lgkmcnt(0)" ::: "memory");
    __builtin_amdgcn_sched_barrier(0);
    __builtin_amdgcn_s_setprio(1);
    MM(4, 2) MM(5, 2) MM(6, 2) MM(7, 2) MM(4, 3) MM(5, 3) MM(6, 3) MM(7, 3)
    __builtin_amdgcn_s_setprio(0);
    __builtin_amdgcn_sched_barrier(0);
    __builtin_amdgcn_s_barrier();
    // phase 3
    if (full) SB(t + 2, 1);
    __builtin_amdgcn_s_barrier();
    __builtin_amdgcn_s_setprio(1);
    MM(4, 0) MM(5, 0) MM(6, 0) MM(7, 0) MM(4, 1) MM(5, 1) MM(6, 1) MM(7, 1)
    __builtin_amdgcn_s_setprio(0);
    if (full) { asm volatile("s_waitcnt vmcnt(8)" ::: "memory"); }
    else      { asm volatile("s_waitcnt vmcnt(0)" ::: "memory"); }
    __builtin_amdgcn_sched_barrier(0);
    __builtin_amdgcn_s_barrier();
  }

  int prow = bm * 256 + wm * 128 + g * 4;
  int pcol = bnc * 256 + wn * 64 + r;
#pragma unroll
  for (int i = 0; i < 8; ++i)
#pragma unroll
    for (int j = 0; j < 4; ++j) {
      int col = pcol + j * 16;
#pragma unroll
      for (int tt = 0; tt < 4; ++tt) {
        int row = prow + i * 16 + tt;
        int b2 = row >> 10, t2 = row & 1023;
        C[(size_t)(b2 * Lsel + t2) * 2048 + col] = f2bf(acc[i][j][tt]);
      }
    }
}
#undef MM

// K-split partial GEMM (final projection)
__global__ __launch_bounds__(256) void gemm_bt_part(
    const ushort_t* __restrict__ A, const ushort_t* __restrict__ Bm, float* __restrict__ P) {
  __shared__ __align__(16) ushort_t lsA[4096];
  __shared__ __align__(16) ushort_t lsB[4096];
  int bn = blockIdx.x, bm = blockIdx.y, s = blockIdx.z;
  f32x4 acc[4][4];
  gemm_core(A, Bm, lsA, lsB, bm, bn, s * 1024, (s + 1) * 1024, acc);
  float* C = P + (size_t)s * 4194304;
  int lane = threadIdx.x & 63, w = threadIdx.x >> 6;
  int g = lane >> 4, r = lane & 15, wm = w >> 1, wn = w & 1;
#pragma unroll
  for (int i = 0; i < 4; ++i)
#pragma unroll
    for (int j = 0; j < 4; ++j) {
      int row0 = bm * 128 + wm * 64 + i * 16 + g * 4;
      int col = bn * 128 + wn * 64 + j * 16 + r;
#pragma unroll
      for (int t = 0; t < 4; ++t)
        C[(size_t)(row0 + t) * 2048 + col] = acc[i][j][t];
    }
}

__global__ __launch_bounds__(256) void add2_kernel(const float* __restrict__ a, const float* __restrict__ b,
                                                   float* __restrict__ out) {
  int i = (blockIdx.x * 256 + threadIdx.x) * 4;
  f32x4 va = *(const f32x4*)(a + i);
  f32x4 vb = *(const f32x4*)(b + i);
  f32x4 r;
#pragma unroll
  for (int k = 0; k < 4; ++k) r[k] = va[k] + vb[k];
  *(f32x4*)(out + i) = r;
}

// ---------- rope / copy bodies ----------
DEV void rope_body(const ushort_t* src, ushort_t* dst, const float* cosT, const float* sinT,
                   int Ls, int s0, int Ld, int dpos0, int cnt, int bp) {
  int b = bp / cnt, pidx = bp % cnt;
  int pos = dpos0 + pidx;
  int pi = threadIdx.x * 4;
  int h = pi >> 6, d = pi & 63;
  const ushort_t* s_ = src + ((size_t)(b * Ls + s0 + pidx) * 16 + h) * 128 + d;
  ushort_t* d_ = dst + ((size_t)(b * Ld + pos) * 16 + h) * 128 + d;
  f32x4 c4 = *(const f32x4*)(cosT + (size_t)pos * 64 + d);
  f32x4 s4 = *(const f32x4*)(sinT + (size_t)pos * 64 + d);
  u16x4 x1 = *(const u16x4*)(s_);
  u16x4 x2 = *(const u16x4*)(s_ + 64);
  u16x4 o1, o2;
#pragma unroll
  for (int k = 0; k < 4; ++k) {
    float a = bf2f(x1[k]), bb = bf2f(x2[k]);
    o1[k] = f2bf(a * c4[k] - bb * s4[k]);
    o2[k] = f2bf(a * s4[k] + bb * c4[k]);
  }
  *(u16x4*)d_ = o1;
  *(u16x4*)(d_ + 64) = o2;
}
DEV void copy_body(const ushort_t* src, ushort_t* dst, int Ls, int s0, int Ld, int dpos0,
                   int cnt, int bp) {
  int b = bp / cnt, pidx = bp % cnt;
  const u32x4* s = (const u32x4*)(src + (size_t)(b * Ls + s0 + pidx) * 2048);
  u32x4* d = (u32x4*)(dst + (size_t)(b * Ld + dpos0 + pidx) * 2048);
  d[threadIdx.x] = s[threadIdx.x];
}

__global__ __launch_bounds__(256) void rope_k(ushort_t* Kc, const float* __restrict__ cosT,
                                              const float* __restrict__ sinT, int L) {
  rope_body(Kc, Kc, cosT, sinT, L, 0, L, 0, 1024, blockIdx.x);
}

__global__ __launch_bounds__(256) void layer1_cache(const ushort_t* __restrict__ K0, ushort_t* __restrict__ K1,
                                                    const ushort_t* __restrict__ V0, ushort_t* __restrict__ V1,
                                                    const float* __restrict__ cosT, const float* __restrict__ sinT) {
  int bp = blockIdx.x;
  if (bp < 2048) rope_body(K0, K1, cosT, sinT, 1024, 0, 2048, 1024, 1024, bp);
  else copy_body(V0, V1, 1024, 0, 2048, 1024, 1024, bp - 2048);
}

__global__ __launch_bounds__(256) void layer2_cache(const ushort_t* __restrict__ K1, ushort_t* __restrict__ K2,
                                                    const ushort_t* __restrict__ V1, ushort_t* __restrict__ V2,
                                                    const float* __restrict__ cosT, const float* __restrict__ sinT) {
  int bp = blockIdx.x;
  if (bp < 2048) copy_body(K1, K2, 2048, 1024, 4096, 1024, 1024, bp);
  else if (bp < 6144) rope_body(K1, K2, cosT, sinT, 2048, 0, 4096, 2048, 2048, bp - 2048);
  else if (bp < 8192) copy_body(V1, V2, 2048, 1024, 4096, 1024, 1024, bp - 6144);
  else copy_body(V1, V2, 2048, 0, 4096, 2048, 2048, bp - 8192);
}

// ---------- flash attention v7: split-KV 3-way, 5 blocks/CU ----------
// Grid = 1536 blocks. Split s handles tiles kt = s, s+3, s+6, ...
__global__ __launch_bounds__(256, 5) void attn_kernel(
    const ushort_t* __restrict__ Qraw, const ushort_t* __restrict__ Kc, const ushort_t* __restrict__ Vc,
    const float* __restrict__ cosT, const float* __restrict__ sinT,
    ushort_t* __restrict__ Opart, float2* __restrict__ Ml, int Lk) {
  __shared__ __align__(16) ushort_t lsK[8192];
  __shared__ __align__(16) ushort_t lsV[8192];
  const float SC2 = 0.1275174366f;  // (1/sqrt(128)) * log2(e)

  int bid = (int)blockIdx.x;
  int swz = (bid & 7) * 192 + (bid >> 3);  // 192 consecutive per XCD; triples co-XCD
  int s = swz % 3;
  int rest = swz / 3;                      // [0,512)

  int w = threadIdx.x >> 6, lane = threadIdx.x & 63;
  int bq = rest & 15, h = (rest >> 4) & 15, b = rest >> 8;
  int qt = bq * 4 + w;
  int g = lane >> 4, r = lane & 15;
  int off = Lk - 1024;

  const ushort_t* qbase = Qraw + ((size_t)(b * 1024 + qt * 16 + r) * 16 + h) * 128;
  int pos = qt * 16 + r;
  const float* cb = cosT + (size_t)pos * 64;
  const float* sb = sinT + (size_t)pos * 64;
  bf16x8 qf[4];
#pragma unroll
  for (int c = 0; c < 2; ++c) {
    int d0 = c * 32 + g * 8;
    f32x4 c0 = *(const f32x4*)(cb + d0);
    f32x4 c1 = *(const f32x4*)(cb + d0 + 4);
    f32x4 s0 = *(const f32x4*)(sb + d0);
    f32x4 s1 = *(const f32x4*)(sb + d0 + 4);
    bf16x8 x1 = *(const bf16x8*)(qbase + d0);
    bf16x8 x2 = *(const bf16x8*)(qbase + d0 + 64);
    bf16x8 lo, hi;
#pragma unroll
    for (int k = 0; k < 8; ++k) {
      float cv = (k < 4 ? c0[k] : c1[k - 4]) * SC2;
      float sv = (k < 4 ? s0[k] : s1[k - 4]) * SC2;
      float a = bf2f((ushort_t)x1[k]);
      float bb = bf2f((ushort_t)x2[k]);
      lo[k] = (short)f2bf(a * cv - bb * sv);
      hi[k] = (short)f2bf(a * sv + bb * cv);
    }
    qf[c] = lo; qf[c + 2] = hi;
  }

  int t = threadIdx.x;
  int krow0 = t >> 4,        kc0 = (t & 15) ^ (krow0 & 7);
  int krow1 = (t + 256) >> 4, kc1 = (t & 15) ^ (krow1 & 7);
  const size_t adv = 32 * 2048;
  const size_t adv3 = 3 * adv;
  const ushort_t* srcK0 = Kc + ((size_t)(b * Lk + krow0) * 16 + h) * 128 + kc0 * 8 + s * adv;
  const ushort_t* srcK1 = Kc + ((size_t)(b * Lk + krow1) * 16 + h) * 128 + kc1 * 8 + s * adv;
  int L0 = t, L1 = t + 256;
  int vrow0 = ((L0 >> 3) & 7) * 4 + ((L0 >> 1) & 3), vd0 = (L0 >> 6) * 16 + (L0 & 1) * 8;
  int vrow1 = ((L1 >> 3) & 7) * 4 + ((L1 >> 1) & 3), vd1 = (L1 >> 6) * 16 + (L1 & 1) * 8;
  const ushort_t* srcV0 = Vc + ((size_t)(b * Lk + vrow0) * 16 + h) * 128 + vd0 + s * adv;
  const ushort_t* srcV1 = Vc + ((size_t)(b * Lk + vrow1) * 16 + h) * 128 + vd1 + s * adv;

  auto STAGE = [&](int buf) {
    ushort_t* k0 = lsK + buf * 4096 + w * 512;
    ushort_t* v0 = lsV + buf * 4096 + w * 512;
    gload_lds16(srcK0, k0);
    gload_lds16(srcK1, k0 + 2048);
    gload_lds16(srcV0, v0);
    gload_lds16(srcV1, v0 + 2048);
    srcK0 += adv3; srcK1 += adv3; srcV0 += adv3; srcV1 += adv3;
  };

  unsigned kx[4];
  unsigned kbase0 = ldsaddr(lsK) + (unsigned)(r * 256);
#pragma unroll
  for (int c = 0; c < 4; ++c)
    kx[c] = kbase0 + (unsigned)((((c * 32 + g * 8) ^ ((r & 7) * 8))) * 2);
  unsigned vbase0 = ldsaddr(lsV);

  float m_run = -1e30f, l_run = 0.f;
  f32x4 o[8];
#pragma unroll
  for (int c = 0; c < 8; ++c) o[c] = 0.f;

  int qp = qt * 16 + r + off;
  int qmin = qt * 16 + off;
  int nkt_w = ((qt * 16 + 15 + off) >> 5) + 1;
  int nkt_blk = (((bq * 4 + 3) * 16 + 15 + off) >> 5) + 1;
  int ntile = (nkt_blk - s + 2) / 3;   // ceil((nkt_blk - s)/3)

#define LDK(c, ks) ldsb128o<(ks) * 4096>(kx[c] + kb)
#define LDV(hh, i) tr16o<(hh) * 4096 + (i) * 512>(vb)

  if (ntile > 0) {
    STAGE(0);
    for (int it = 0; it < ntile; ++it) {
      int kt = s + it * 3;
      int cur = it & 1;
      if (it + 1 < ntile) {
        STAGE(cur ^ 1);
        asm volatile("s_waitcnt vmcnt(4)" ::: "memory");
      } else {
        asm volatile("s_waitcnt vmcnt(0)" ::: "memory");
      }
      __builtin_amdgcn_s_barrier();
      __builtin_amdgcn_sched_barrier(0);
      if (kt < nkt_w) {
        unsigned kb = (unsigned)(cur << 13);
        unsigned vb = vbase0 + kb;
        f32x4 st[2];
        {
          bf16x8 k0 = LDK(0, 0), k1 = LDK(1, 0), k2 = LDK(2, 0), k3 = LDK(3, 0);
          asm volatile("s_waitcnt lgkmcnt(0)" ::: "memory");
          __builtin_amdgcn_sched_barrier(0);
          __builtin_amdgcn_s_setprio(1);
          f32x4 acc = 0.f;
          acc = __builtin_amdgcn_mfma_f32_16x16x32_bf16(k0, qf[0], acc, 0, 0, 0);
          acc = __builtin_amdgcn_mfma_f32_16x16x32_bf16(k1, qf[1], acc, 0, 0, 0);
          acc = __builtin_amdgcn_mfma_f32_16x16x32_bf16(k2, qf[2], acc, 0, 0, 0);
          acc = __builtin_amdgcn_mfma_f32_16x16x32_bf16(k3, qf[3], acc, 0, 0, 0);
          __builtin_amdgcn_s_setprio(0);
          st[0] = acc;
        }
        {
          bf16x8 k0 = LDK(0, 1), k1 = LDK(1, 1), k2 = LDK(2, 1), k3 = LDK(3, 1);
          asm volatile("s_waitcnt lgkmcnt(0)" ::: "memory");
          __builtin_amdgcn_sched_barrier(0);
          __builtin_amdgcn_s_setprio(1);
          f32x4 acc = 0.f;
          acc = __builtin_amdgcn_mfma_f32_16x16x32_bf16(k0, qf[0], acc, 0, 0, 0);
          acc = __builtin_amdgcn_mfma_f32_16x16x32_bf16(k1, qf[1], acc, 0, 0, 0);
          acc = __builtin_amdgcn_mfma_f32_16x16x32_bf16(k2, qf[2], acc, 0, 0, 0);
          acc = __builtin_amdgcn_mfma_f32_16x16x32_bf16(k3, qf[3], acc, 0, 0, 0);
          __builtin_amdgcn_s_setprio(0);
          st[1] = acc;
        }
        // softmax (log2 domain)
        float pmaxl = -1e30f;   // lane-local max
        int kp0 = kt * 32;
        if (kp0 + 31 > qmin) {
#pragma unroll
          for (int ks = 0; ks < 2; ++ks)
#pragma unroll
            for (int j = 0; j < 4; ++j) {
              int key = kp0 + ks * 16 + g * 4 + j;
              float sv = st[ks][j];
              if (key > qp) sv = -1e30f;
              st[ks][j] = sv;
              pmaxl = fmaxf(pmaxl, sv);
            }
        } else {
#pragma unroll
          for (int ks = 0; ks < 2; ++ks)
#pragma unroll
            for (int j = 0; j < 4; ++j) pmaxl = fmaxf(pmaxl, st[ks][j]);
        }
        // fast path: if no lane's local max exceeds threshold, global max doesn't either
        if (!__all(pmaxl <= m_run + 11.5f)) {
          float pmax = fmaxf(pmaxl, __shfl_xor(pmaxl, 16, 64));
          pmax = fmaxf(pmax, __shfl_xor(pmax, 32, 64));
          if (pmax > m_run + 11.5f) {
            float mnew = fmaxf(m_run, pmax);
            float corr = exp2f(m_run - mnew);
            l_run *= corr;
#pragma unroll
            for (int c = 0; c < 8; ++c)
#pragma unroll
              for (int tt = 0; tt < 4; ++tt) o[c][tt] *= corr;
            m_run = mnew;
          }
        }
        float psum = 0.f;
        bf16x4 pf[2];
#pragma unroll
        for (int ks = 0; ks < 2; ++ks)
#pragma unroll
          for (int j = 0; j < 4; ++j) {
            float pe = exp2f(st[ks][j] - m_run);
            psum += pe;
            pf[ks][j] = (short)f2bf(pe);
          }
        psum += __shfl_xor(psum, 16, 64);
        psum += __shfl_xor(psum, 32, 64);
        l_run += psum;
        {
          bf16x4 v0 = LDV(0, 0), v1 = LDV(0, 1), v2 = LDV(0, 2), v3 = LDV(0, 3);
          bf16x4 v4 = LDV(0, 4), v5 = LDV(0, 5), v6 = LDV(0, 6), v7 = LDV(0, 7);
          asm volatile("s_waitcnt lgkmcnt(0)" ::: "memory");
          __builtin_amdgcn_sched_barrier(0);
          __builtin_amdgcn_s_setprio(1);
          o[0] = __builtin_amdgcn_mfma_f32_16x16x16bf16_1k(v0, pf[0], o[0], 0, 0, 0);
          o[0] = __builtin_amdgcn_mfma_f32_16x16x16bf16_1k(v1, pf[1], o[0], 0, 0, 0);
          o[1] = __builtin_amdgcn_mfma_f32_16x16x16bf16_1k(v2, pf[0], o[1], 0, 0, 0);
          o[1] = __builtin_amdgcn_mfma_f32_16x16x16bf16_1k(v3, pf[1], o[1], 0, 0, 0);
          o[2] = __builtin_amdgcn_mfma_f32_16x16x16bf16_1k(v4, pf[0], o[2], 0, 0, 0);
          o[2] = __builtin_amdgcn_mfma_f32_16x16x16bf16_1k(v5, pf[1], o[2], 0, 0, 0);
          o[3] = __builtin_amdgcn_mfma_f32_16x16x16bf16_1k(v6, pf[0], o[3], 0, 0, 0);
          o[3] = __builtin_amdgcn_mfma_f32_16x16x16bf16_1k(v7, pf[1], o[3], 0, 0, 0);
          __builtin_amdgcn_s_setprio(0);
        }
        {
          bf16x4 v0 = LDV(1, 0), v1 = LDV(1, 1), v2 = LDV(1, 2), v3 = LDV(1, 3);
          bf16x4 v4 = LDV(1, 4), v5 = LDV(1, 5), v6 = LDV(1, 6), v7 = LDV(1, 7);
          asm volatile("s_waitcnt lgkmcnt(0)" ::: "memory");
          __builtin_amdgcn_sched_barrier(0);
          __builtin_amdgcn_s_setprio(1);
          o[4] = __builtin_amdgcn_mfma_f32_16x16x16bf16_1k(v0, pf[0], o[4], 0, 0, 0);
          o[4] = __builtin_amdgcn_mfma_f32_16x16x16bf16_1k(v1, pf[1], o[4], 0, 0, 0);
          o[5] = __builtin_amdgcn_mfma_f32_16x16x16bf16_1k(v2, pf[0], o[5], 0, 0, 0);
          o[5] = __builtin_amdgcn_mfma_f32_16x16x16bf16_1k(v3, pf[1], o[5], 0, 0, 0);
          o[6] = __builtin_amdgcn_mfma_f32_16x16x16bf16_1k(v4, pf[0], o[6], 0, 0, 0);
          o[6] = __builtin_amdgcn_mfma_f32_16x16x16bf16_1k(v5, pf[1], o[6], 0, 0, 0);
          o[7] = __builtin_amdgcn_mfma_f32_16x16x16bf16_1k(v6, pf[0], o[7], 0, 0, 0);
          o[7] = __builtin_amdgcn_mfma_f32_16x16x16bf16_1k(v7, pf[1], o[7], 0, 0, 0);
          __builtin_amdgcn_s_setprio(0);
        }
      }
      __builtin_amdgcn_sched_barrier(0);
      __builtin_amdgcn_s_barrier();
    }
  }
#undef LDK
#undef LDV
  ushort_t* ob = Opart + (size_t)s * 4194304 + ((size_t)(b * 1024 + qt * 16 + r) * 16 + h) * 128;
#pragma unroll
  for (int dblk = 0; dblk < 8; ++dblk) {
    u16x4 ov;
#pragma unroll
    for (int tt = 0; tt < 4; ++tt) ov[tt] = f2bf(o[dblk][tt]);
    *(u16x4*)(ob + dblk * 16 + g * 4) = ov;
  }
  if (g == 0) {
    float2 ml; ml.x = m_run; ml.y = l_run;
    Ml[((size_t)(s * 2 + b) * 1024 + qt * 16 + r) * 16 + h] = ml;
  }
}

// ---------- combine 3 split partials (bf16, log2-domain m) + RMS norm + accumulate ----------
template <int FIRST>
__global__ __launch_bounds__(256) void rms_combine(const ushort_t* __restrict__ Opart, const float2* __restrict__ Ml,
                                                   const float* __restrict__ lnw, const float* __restrict__ lam,
                                                   int li, float* __restrict__ total) {
  int row = blockIdx.x;
  int t8 = threadIdx.x * 8;
  int h = t8 >> 7;
  float2 ml0 = Ml[(size_t)row * 16 + h];
  float2 ml1 = Ml[(size_t)(row + 2048) * 16 + h];
  float2 ml2 = Ml[(size_t)(row + 4096) * 16 + h];
  float M = fmaxf(fmaxf(ml0.x, ml1.x), ml2.x);
  float w0 = exp2f(ml0.x - M), w1 = exp2f(ml1.x - M), w2 = exp2f(ml2.x - M);
  float rinv = 1.f / (w0 * ml0.y + w1 * ml1.y + w2 * ml2.y);
  w0 *= rinv; w1 *= rinv; w2 *= rinv;
  const ushort_t* a0 = Opart + (size_t)row * 2048 + t8;
  const ushort_t* a1 = a0 + 4194304;
  const ushort_t* a2 = a0 + 2 * 4194304;
  u16x4 p00 = *(const u16x4*)(a0);
  u16x4 p01 = *(const u16x4*)(a0 + 4);
  u16x4 p10 = *(const u16x4*)(a1);
  u16x4 p11 = *(const u16x4*)(a1 + 4);
  u16x4 p20 = *(const u16x4*)(a2);
  u16x4 p21 = *(const u16x4*)(a2 + 4);
  f32x4 v0, v1;
#pragma unroll
  for (int k = 0; k < 4; ++k) {
    v0[k] = w0 * bf2f(p00[k]) + w1 * bf2f(p10[k]) + w2 * bf2f(p20[k]);
    v1[k] = w0 * bf2f(p01[k]) + w1 * bf2f(p11[k]) + w2 * bf2f(p21[k]);
  }
  float ss = v0.x * v0.x + v0.y * v0.y + v0.z * v0.z + v0.w * v0.w +
             v1.x * v1.x + v1.y * v1.y + v1.z * v1.z + v1.w * v1.w;
#pragma unroll
  for (int m = 1; m < 64; m <<= 1) ss += __shfl_xor(ss, m, 64);
  __shared__ float red[4];
  int w = threadIdx.x >> 6, lane = threadIdx.x & 63;
  if (lane == 0) red[w] = ss;
  __syncthreads();
  ss = red[0] + red[1] + red[2] + red[3];
  float sca = rsqrtf(ss * (1.f / 2048.f) + 1e-5f) * lam[li];
  f32x4 w0v = *(const f32x4*)(lnw + t8);
  f32x4 w1v = *(const f32x4*)(lnw + t8 + 4);
  float* o = total + (size_t)row * 2048 + t8;
  f32x4 r0, r1;
#pragma unroll
  for (int k = 0; k < 4; ++k) { r0[k] = v0[k] * sca * w0v[k]; r1[k] = v1[k] * sca * w1v[k]; }
  if (!FIRST) {
    f32x4 q0 = *(const f32x4*)(o);
    f32x4 q1 = *(const f32x4*)(o + 4);
#pragma unroll
    for (int k = 0; k < 4; ++k) { r0[k] += q0[k]; r1[k] += q1[k]; }
  }
  *(f32x4*)(o) = r0;
  *(f32x4*)(o + 4) = r1;
}

// ---------- final: y = rms(total + alpha*x)*flw -> bf16 ----------
__global__ __launch_bounds__(256) void final_norm(const float* __restrict__ total, const float* __restrict__ x,
                                                  const float* __restrict__ alphap, const float* __restrict__ flw,
                                                  ushort_t* __restrict__ ybf) {
  int row = blockIdx.x;
  float al = alphap[0];
  int t8 = threadIdx.x * 8;
  const float* tp = total + (size_t)row * 2048 + t8;
  const float* xp = x + (size_t)row * 2048 + t8;
  f32x4 t0 = *(const f32x4*)(tp);
  f32x4 t1 = *(const f32x4*)(tp + 4);
  f32x4 x0 = *(const f32x4*)(xp);
  f32x4 x1 = *(const f32x4*)(xp + 4);
  float y[8];
#pragma unroll
  for (int k = 0; k < 4; ++k) { y[k] = t0[k] + al * x0[k]; y[4 + k] = t1[k] + al * x1[k]; }
  float ss = 0.f;
#pragma unroll
  for (int k = 0; k < 8; ++k) ss += y[k] * y[k];
#pragma unroll
  for (int m = 1; m < 64; m <<= 1) ss += __shfl_xor(ss, m, 64);
  __shared__ float red[4];
  int w = threadIdx.x >> 6, lane = threadIdx.x & 63;
  if (lane == 0) red[w] = ss;
  __syncthreads();
  ss = red[0] + red[1] + red[2] + red[3];
  float s = rsqrtf(ss * (1.f / 2048.f) + 1e-5f);
  f32x4 w0 = *(const f32x4*)(flw + t8);
  f32x4 w1 = *(const f32x4*)(flw + t8 + 4);
  u16x4 o0, o1;
#pragma unroll
  for (int k = 0; k < 4; ++k) {
    o0[k] = f2bf(y[k] * s * w0[k]);
    o1[k] = f2bf(y[4 + k] * s * w1[k]);
  }
  *(u16x4*)(ybf + (size_t)row * 2048 + t8) = o0;
  *(u16x4*)(ybf + (size_t)row * 2048 + t8 + 4) = o1;
}

// ---------- host ----------
extern "C" void kernel_launch(void* const* d_in, const int* in_sizes, int n_in,
                              void* d_out, int out_size, void* d_ws, size_t ws_size,
                              hipStream_t stream) {
  const float* x = (const float*)d_in[0];
  const float* cosT = (const float*)d_in[1];
  const float* sinT = (const float*)d_in[2];
  const float* wq = (const float*)d_in[3];
  const float* wk = (const float*)d_in[4];
  const float* wv = (const float*)d_in[5];
  const float* lnw = (const float*)d_in[6];
  const float* lambdas = (const float*)d_in[7];
  const float* w_out = (const float*)d_in[8];
  const float* flw = (const float*)d_in[9];
  const float* alpha = (const float*)d_in[10];

  const size_t ME = 4194304ull;
  char* p = (char*)d_ws;
  size_t off = 0;
  auto alc = [&](size_t bytes) -> void* {
    void* r = p + off;
    off += (bytes + 255) & ~(size_t)255;
    return r;
  };
  ushort_t* xb = (ushort_t*)alc(ME * 2);
  void* uni = alc(2 * ME * 4);                // 32 MB union: wl(24) / Opart-bf16(24) / Ppart(32)
  ushort_t* wl = (ushort_t*)uni;
  ushort_t* Opart = (ushort_t*)uni;
  float* Ppart = (float*)uni;
  ushort_t* q = (ushort_t*)alc(ME * 2);
  ushort_t* K0 = (ushort_t*)alc(ME * 2);
  ushort_t* K1 = (ushort_t*)alc(2 * ME * 2);
  ushort_t* K2 = (ushort_t*)alc(4 * ME * 2);
  ushort_t* V0 = (ushort_t*)alc(ME * 2);
  ushort_t* V1 = (ushort_t*)alc(2 * ME * 2);
  ushort_t* V2 = (ushort_t*)alc(4 * ME * 2);
  float* total = (float*)alc(ME * 4);
  float2* Ml = (float2*)alc(98304 * 8);       // 6 slots x 1024 x 16 (3 splits x 2 batch)
  float* lam = (float*)alc(256);
  ushort_t* ybf = q;
  ushort_t* wob = K0;

  f2b_kernel<<<4096, 256, 0, stream>>>(x, xb, 4194304);
  lam_kernel<<<1, 64, 0, stream>>>(lambdas, lam);

  ushort_t* Kc[3] = {K0, K1, K2};
  ushort_t* Vc[3] = {V0, V1, V2};

  for (int li = 0; li < 3; ++li) {
    int L = 1024 << li;
    size_t woff = (size_t)li * ME;
    f2b3_kernel<<<12288, 256, 0, stream>>>(wq + woff, wk + woff, wv + woff, wl);
    gemm_qkv256<<<192, 512, 0, stream>>>(xb, wl, wl + ME, wl + 2 * ME,
                                         q, Kc[li], Vc[li], L);
    rope_k<<<2048, 256, 0, stream>>>(Kc[li], cosT, sinT, L);
    if (li == 1)
      layer1_cache<<<4096, 256, 0, stream>>>(K0, K1, V0, V1, cosT, sinT);
    else if (li == 2)
      layer2_cache<<<12288, 256, 0, stream>>>(K1, K2, V1, V2, cosT, sinT);
    attn_kernel<<<1536, 256, 0, stream>>>(q, Kc[li], Vc[li], cosT, sinT, Opart, Ml, L);
    if (li == 0)
      rms_combine<1><<<2048, 256, 0, stream>>>(Opart, Ml, lnw, lam, 0, total);
    else
      rms_combine<0><<<2048, 256, 0, stream>>>(Opart, Ml, lnw + (size_t)li * 2048, lam, li, total);
  }

  f2b_kernel<<<4096, 256, 0, stream>>>(w_out, wob, 4194304);
  final_norm<<<2048, 256, 0, stream>>>(total, x, alpha, flw, ybf);
  gemm_bt_part<<<dim3(16, 16, 2), 256, 0, stream>>>(ybf, wob, Ppart);
  add2_kernel<<<4096, 256, 0, stream>>>(Ppart, Ppart + ME, (float*)d_out);
}

// Round 12
// 555.368 us; speedup vs baseline: 1.5277x; 1.5277x over previous
//
#include <hip/hip_runtime.h>
#include <hip/hip_bf16.h>

typedef unsigned short ushort_t;
typedef __attribute__((ext_vector_type(8))) short bf16x8;
typedef __attribute__((ext_vector_type(4))) short bf16x4;
typedef __attribute__((ext_vector_type(4))) float f32x4;
typedef __attribute__((ext_vector_type(4))) unsigned short u16x4;
typedef __attribute__((ext_vector_type(4))) unsigned int u32x4;

#define DEV __device__ __forceinline__

// ---------- helpers ----------
DEV ushort_t f2bf(float f) {
  __hip_bfloat16 h = __float2bfloat16(f);   // hardware RNE convert
  return __builtin_bit_cast(unsigned short, h);
}
DEV float bf2f(ushort_t b) {
  union { float f; unsigned int u; } a; a.u = ((unsigned int)b) << 16;
  return a.f;
}
DEV void gload_lds16(const void* g, void* l) {
  __builtin_amdgcn_global_load_lds((const __attribute__((address_space(1))) void*)g,
                                   (__attribute__((address_space(3))) void*)l, 16, 0, 0);
}
DEV unsigned ldsaddr(const void* l) {
  return (unsigned)(unsigned long long)(const __attribute__((address_space(3))) void*)l;
}
template <int OFF>
DEV bf16x4 tr16o(unsigned a) {
  bf16x4 d;
  asm volatile("ds_read_b64_tr_b16 %0, %1 offset:%c2" : "=v"(d) : "v"(a), "i"(OFF));
  return d;
}
template <int OFF>
DEV bf16x8 ldsb128o(unsigned a) {
  bf16x8 d;
  asm volatile("ds_read_b128 %0, %1 offset:%c2" : "=v"(d) : "v"(a), "i"(OFF));
  return d;
}

// ---------- f32 -> bf16 convert ----------
__global__ __launch_bounds__(256) void f2b_kernel(const float* __restrict__ in,
                                                  ushort_t* __restrict__ out, int n) {
  int base = (blockIdx.x * 256 + threadIdx.x) * 4;
  if (base >= n) return;
  f32x4 v = *(const f32x4*)(in + base);
  u16x4 o;
  o.x = f2bf(v.x); o.y = f2bf(v.y); o.z = f2bf(v.z); o.w = f2bf(v.w);
  *(u16x4*)(out + base) = o;
}

// fused 3-tensor convert (per-layer wq/wk/wv)
__global__ __launch_bounds__(256) void f2b3_kernel(const float* __restrict__ a, const float* __restrict__ b,
                                                   const float* __restrict__ c, ushort_t* __restrict__ out) {
  int id = blockIdx.x * 256 + threadIdx.x;
  int sel = id >> 20, k = (id & 1048575) * 4;
  const float* src = sel == 0 ? a : sel == 1 ? b : c;
  f32x4 v = *(const f32x4*)(src + k);
  u16x4 o;
  o.x = f2bf(v.x); o.y = f2bf(v.y); o.z = f2bf(v.z); o.w = f2bf(v.w);
  *(u16x4*)(out + (size_t)sel * 4194304 + k) = o;
}

// ---------- lambda weights ----------
__global__ void lam_kernel(const float* __restrict__ lambdas, float* __restrict__ lam) {
  if (threadIdx.x == 0 && blockIdx.x == 0) {
    float l0 = 1.f / (1.f + __expf(-lambdas[0]));
    float l1 = 1.f / (1.f + __expf(-lambdas[1]));
    float l2 = 1.f / (1.f + __expf(-lambdas[2]));
    float mean = (l0 + l1 + l2) * (1.f / 3.f);
    float d0 = l0 - mean, d1 = l1 - mean, d2 = l2 - mean;
    float var = (d0 * d0 + d1 * d1 + d2 * d2) * (1.f / 3.f);
    float rs = rsqrtf(var + 1e-5f);
    lam[0] = d0 * rs; lam[1] = d1 * rs; lam[2] = d2 * rs;
  }
}

// ---------- legacy 128x128 GEMM core (final projection) ----------
DEV void gemm_core(const ushort_t* __restrict__ A, const ushort_t* __restrict__ Bm,
                   ushort_t* lsA, ushort_t* lsB, int bm, int bn, int kbeg, int kend,
                   f32x4 (&acc)[4][4]) {
  const int K = 2048;
  int tid = threadIdx.x;
  int w = tid >> 6, lane = tid & 63;
  int g = lane >> 4, r = lane & 15;
  int wm = w >> 1, wn = w & 1;
#pragma unroll
  for (int i = 0; i < 4; ++i)
#pragma unroll
    for (int j = 0; j < 4; ++j) acc[i][j] = 0.f;

  for (int kk = kbeg; kk < kend; kk += 32) {
    __syncthreads();
#pragma unroll
    for (int j2 = 0; j2 < 2; ++j2) {
      int eb = w * 1024 + j2 * 512;
      int ebl = eb + lane * 8;
      int rr = ebl >> 5, cc = ebl & 31;
      gload_lds16(A + (size_t)(bm * 128 + rr) * K + kk + cc, lsA + eb);
      gload_lds16(Bm + (size_t)(bn * 128 + rr) * K + kk + cc, lsB + eb);
    }
    __syncthreads();
    bf16x8 af[4], bfr[4];
#pragma unroll
    for (int i = 0; i < 4; ++i)
      af[i] = *(const bf16x8*)(lsA + (wm * 64 + i * 16 + r) * 32 + g * 8);
#pragma unroll
    for (int j = 0; j < 4; ++j)
      bfr[j] = *(const bf16x8*)(lsB + (wn * 64 + j * 16 + r) * 32 + g * 8);
#pragma unroll
    for (int i = 0; i < 4; ++i)
#pragma unroll
      for (int j = 0; j < 4; ++j)
        acc[i][j] = __builtin_amdgcn_mfma_f32_16x16x32_bf16(af[i], bfr[j], acc[i][j], 0, 0, 0);
  }
}

// ---------- 8-phase 256x256 fused QKV GEMM (proven round 10) + V multi-dest epilogue ----------
#define MM(i, j)                                                                              \
  acc[i][j] = __builtin_amdgcn_mfma_f32_16x16x32_bf16(af[(i) & 3][0], bfr[j][0], acc[i][j], 0, 0, 0); \
  acc[i][j] = __builtin_amdgcn_mfma_f32_16x16x32_bf16(af[(i) & 3][1], bfr[j][1], acc[i][j], 0, 0, 0);

__global__ __launch_bounds__(512, 2) void gemm_qkv256(
    const ushort_t* __restrict__ A,
    const ushort_t* __restrict__ Bq, const ushort_t* __restrict__ Bk, const ushort_t* __restrict__ Bv,
    ushort_t* __restrict__ Cq, ushort_t* __restrict__ Ck, ushort_t* __restrict__ Cv, int Lkv,
    ushort_t* __restrict__ ve0, size_t vs0,
    ushort_t* __restrict__ ve1, size_t vs1,
    ushort_t* __restrict__ ve2, size_t vs2) {
  __shared__ __align__(16) ushort_t lsA[32768];
  __shared__ __align__(16) ushort_t lsB[32768];
  const int NT = 32;

  int bid = (int)blockIdx.x;
  int swz = (bid & 7) * 24 + (bid >> 3);
  int bm = swz / 24;
  int rest = swz % 24;
  int sel = rest >> 3, bnc = rest & 7;
  const ushort_t* Bmat = (sel == 0) ? Bq : (sel == 1) ? Bk : Bv;
  ushort_t* C = (sel == 0) ? Cq : (sel == 1) ? Ck : Cv;
  int Lsel = (sel == 0) ? 1024 : Lkv;

  int tid = threadIdx.x;
  int wv = tid >> 6, lane = tid & 63;
  int wm = wv >> 2, wn = wv & 3;
  int g = lane >> 4, r = lane & 15;

  int row0 = tid >> 3, c0 = tid & 7;
  int colsw = (c0 ^ (row0 & 7)) * 8;
  const ushort_t* pA0 = A + (size_t)(bm * 256 + row0) * 2048 + colsw;
  const ushort_t* pB0 = Bmat + (size_t)(bnc * 256 + row0) * 2048 + colsw;
  ushort_t* dA = lsA + tid * 8;
  ushort_t* dB = lsB + tid * 8;

  auto SA = [&](int T, int hh) {
    const ushort_t* s = pA0 + (size_t)(hh * 128) * 2048 + (size_t)T * 64;
    ushort_t* d = dA + (T & 1) * 16384 + hh * 8192;
    gload_lds16(s, d);
    gload_lds16(s + (size_t)64 * 2048, d + 4096);
  };
  auto SB = [&](int T, int hh) {
    const ushort_t* s = pB0 + (size_t)(hh * 128) * 2048 + (size_t)T * 64;
    ushort_t* d = dB + (T & 1) * 16384 + hh * 8192;
    gload_lds16(s, d);
    gload_lds16(s + (size_t)64 * 2048, d + 4096);
  };

  unsigned xm = (unsigned)(r & 7);
  unsigned aAb = ldsaddr(lsA) + (unsigned)((wm * 128 + r) * 128);
  unsigned aA0b = aAb + ((((unsigned)g) ^ xm) << 4);
  unsigned aA1b = aAb + ((((unsigned)(4 + g)) ^ xm) << 4);
  unsigned aBb = ldsaddr(lsB) + (unsigned)((wn * 64 + r) * 128);
  unsigned aB0b = aBb + ((((unsigned)g) ^ xm) << 4);
  unsigned aB1b = aBb + ((((unsigned)(4 + g)) ^ xm) << 4);

  f32x4 acc[8][4];
#pragma unroll
  for (int i = 0; i < 8; ++i)
#pragma unroll
    for (int j = 0; j < 4; ++j) acc[i][j] = 0.f;
  bf16x8 af[4][2], bfr[4][2];

  SA(0, 0); SB(0, 0); SB(0, 1); SA(0, 1);
  SA(1, 0); SB(1, 0); SB(1, 1);
  asm volatile("s_waitcnt vmcnt(6)" ::: "memory");
  __builtin_amdgcn_s_barrier();
  __builtin_amdgcn_sched_barrier(0);

  for (int t = 0; t < NT; ++t) {
    unsigned cb = (unsigned)((t & 1) << 15);
    unsigned A0 = aA0b + cb, A1 = aA1b + cb, B0 = aB0b + cb, B1 = aB1b + cb;
    bool full = (t < NT - 2);
    // phase 0
    af[0][0] = ldsb128o<0>(A0);     af[0][1] = ldsb128o<0>(A1);
    af[1][0] = ldsb128o<2048>(A0);  af[1][1] = ldsb128o<2048>(A1);
    af[2][0] = ldsb128o<4096>(A0);  af[2][1] = ldsb128o<4096>(A1);
    af[3][0] = ldsb128o<6144>(A0);  af[3][1] = ldsb128o<6144>(A1);
    bfr[0][0] = ldsb128o<0>(B0);    bfr[0][1] = ldsb128o<0>(B1);
    bfr[1][0] = ldsb128o<2048>(B0); bfr[1][1] = ldsb128o<2048>(B1);
    if (t + 1 < NT) SA(t + 1, 1);
    __builtin_amdgcn_s_barrier();
    asm volatile("s_waitcnt lgkmcnt(0)" ::: "memory");
    __builtin_amdgcn_sched_barrier(0);
    __builtin_amdgcn_s_setprio(1);
    MM(0, 0) MM(1, 0) MM(2, 0) MM(3, 0) MM(0, 1) MM(1, 1) MM(2, 1) MM(3, 1)
    __builtin_amdgcn_s_setprio(0);
    __builtin_amdgcn_sched_barrier(0);
    __builtin_amdgcn_s_barrier();
    // phase 1
    bfr[2][0] = ldsb128o<4096>(B0); bfr[2][1] = ldsb128o<4096>(B1);
    bfr[3][0] = ldsb128o<6144>(B0); bfr[3][1] = ldsb128o<6144>(B1);
    if (full) SA(t + 2, 0);
    __builtin_amdgcn_s_barrier();
    asm volatile("s_waitcnt lgkmcnt(0)" ::: "memory");
    __builtin_amdgcn_sched_barrier(0);
    __builtin_amdgcn_s_setprio(1);
    MM(0, 2) MM(1, 2) MM(2, 2) MM(3, 2) MM(0, 3) MM(1, 3) MM(2, 3) MM(3, 3)
    __builtin_amdgcn_s_setprio(0);
    if (full) { asm volatile("s_waitcnt vmcnt(4)" ::: "memory"); }
    else      { asm volatile("s_waitcnt vmcnt(0)" ::: "memory"); }
    __builtin_amdgcn_sched_barrier(0);
    __builtin_amdgcn_s_barrier();
    // phase 2
    af[0][0] = ldsb128o<8192>(A0);  af[0][1] = ldsb128o<8192>(A1);
    af[1][0] = ldsb128o<10240>(A0); af[1][1] = ldsb128o<10240>(A1);
    af[2][0] = ldsb128o<12288>(A0); af[2][1] = ldsb128o<12288>(A1);
    af[3][0] = ldsb128o<14336>(A0); af[3][1] = ldsb128o<14336>(A1);
    if (full) SB(t + 2, 0);
    __builtin_amdgcn_s_barrier();
    asm volatile("s_waitcnt lgkmcnt(0)" ::: "memory");
    __builtin_amdgcn_sched_barrier(0);
    __builtin_amdgcn_s_setprio(1);
    MM(4, 2) MM(5, 2) MM(6, 2) MM(7, 2) MM(4, 3) MM(5, 3) MM(6, 3) MM(7, 3)
    __builtin_amdgcn_s_setprio(0);
    __builtin_amdgcn_sched_barrier(0);
    __builtin_amdgcn_s_barrier();
    // phase 3
    if (full) SB(t + 2, 1);
    __builtin_amdgcn_s_barrier();
    __builtin_amdgcn_s_setprio(1);
    MM(4, 0) MM(5, 0) MM(6, 0) MM(7, 0) MM(4, 1) MM(5, 1) MM(6, 1) MM(7, 1)
    __builtin_amdgcn_s_setprio(0);
    if (full) { asm volatile("s_waitcnt vmcnt(8)" ::: "memory"); }
    else      { asm volatile("s_waitcnt vmcnt(0)" ::: "memory"); }
    __builtin_amdgcn_sched_barrier(0);
    __builtin_amdgcn_s_barrier();
  }

  int prow = bm * 256 + wm * 128 + g * 4;
  int pcol = bnc * 256 + wn * 64 + r;
#pragma unroll
  for (int i = 0; i < 8; ++i)
#pragma unroll
    for (int j = 0; j < 4; ++j) {
      int col = pcol + j * 16;
#pragma unroll
      for (int tt = 0; tt < 4; ++tt) {
        int row = prow + i * 16 + tt;
        int b2 = row >> 10, t2 = row & 1023;
        ushort_t val = f2bf(acc[i][j][tt]);
        C[(size_t)(b2 * Lsel + t2) * 2048 + col] = val;
        if (sel == 2) {  // V cache replication (fused copy_seg)
          size_t rc = (size_t)t2 * 2048 + col;
          if (ve0) ve0[(size_t)b2 * vs0 + rc] = val;
          if (ve1) ve1[(size_t)b2 * vs1 + rc] = val;
          if (ve2) ve2[(size_t)b2 * vs2 + rc] = val;
        }
      }
    }
}
#undef MM

// K-split partial GEMM (final projection)
__global__ __launch_bounds__(256) void gemm_bt_part(
    const ushort_t* __restrict__ A, const ushort_t* __restrict__ Bm, float* __restrict__ P) {
  __shared__ __align__(16) ushort_t lsA[4096];
  __shared__ __align__(16) ushort_t lsB[4096];
  int bn = blockIdx.x, bm = blockIdx.y, s = blockIdx.z;
  f32x4 acc[4][4];
  gemm_core(A, Bm, lsA, lsB, bm, bn, s * 1024, (s + 1) * 1024, acc);
  float* C = P + (size_t)s * 4194304;
  int lane = threadIdx.x & 63, w = threadIdx.x >> 6;
  int g = lane >> 4, r = lane & 15, wm = w >> 1, wn = w & 1;
#pragma unroll
  for (int i = 0; i < 4; ++i)
#pragma unroll
    for (int j = 0; j < 4; ++j) {
      int row0 = bm * 128 + wm * 64 + i * 16 + g * 4;
      int col = bn * 128 + wn * 64 + j * 16 + r;
#pragma unroll
      for (int t = 0; t < 4; ++t)
        C[(size_t)(row0 + t) * 2048 + col] = acc[i][j][t];
    }
}

__global__ __launch_bounds__(256) void add2_kernel(const float* __restrict__ a, const float* __restrict__ b,
                                                   float* __restrict__ out) {
  int i = (blockIdx.x * 256 + threadIdx.x) * 4;
  f32x4 va = *(const f32x4*)(a + i);
  f32x4 vb = *(const f32x4*)(b + i);
  f32x4 r;
#pragma unroll
  for (int k = 0; k < 4; ++k) r[k] = va[k] + vb[k];
  *(f32x4*)(out + i) = r;
}

// ---------- rope body ----------
DEV void rope_body(const ushort_t* src, ushort_t* dst, const float* cosT, const float* sinT,
                   int Ls, int s0, int Ld, int dpos0, int cnt, int bp) {
  int b = bp / cnt, pidx = bp % cnt;
  int pos = dpos0 + pidx;
  int pi = threadIdx.x * 4;
  int h = pi >> 6, d = pi & 63;
  const ushort_t* s_ = src + ((size_t)(b * Ls + s0 + pidx) * 16 + h) * 128 + d;
  ushort_t* d_ = dst + ((size_t)(b * Ld + pos) * 16 + h) * 128 + d;
  f32x4 c4 = *(const f32x4*)(cosT + (size_t)pos * 64 + d);
  f32x4 s4 = *(const f32x4*)(sinT + (size_t)pos * 64 + d);
  u16x4 x1 = *(const u16x4*)(s_);
  u16x4 x2 = *(const u16x4*)(s_ + 64);
  u16x4 o1, o2;
#pragma unroll
  for (int k = 0; k < 4; ++k) {
    float a = bf2f(x1[k]), bb = bf2f(x2[k]);
    o1[k] = f2bf(a * c4[k] - bb * s4[k]);
    o2[k] = f2bf(a * s4[k] + bb * c4[k]);
  }
  *(u16x4*)d_ = o1;
  *(u16x4*)(d_ + 64) = o2;
}

__global__ __launch_bounds__(256) void rope_k(ushort_t* Kc, const float* __restrict__ cosT,
                                              const float* __restrict__ sinT, int L) {
  rope_body(Kc, Kc, cosT, sinT, L, 0, L, 0, 1024, blockIdx.x);
}

// layer1 cache build: K1[1024:2048) = K2[1024:2048) = rope(K0, pos+1024)  (dual-dest)
__global__ __launch_bounds__(256) void layer1_cache(const ushort_t* __restrict__ K0, ushort_t* __restrict__ K1,
                                                    ushort_t* __restrict__ K2,
                                                    const float* __restrict__ cosT, const float* __restrict__ sinT) {
  int bp = blockIdx.x;
  int b = bp >> 10, pidx = bp & 1023;
  int pos = 1024 + pidx;
  int pi = threadIdx.x * 4;
  int h = pi >> 6, d = pi & 63;
  size_t io = ((size_t)h) * 128 + d;
  const ushort_t* s_ = K0 + ((size_t)(b * 1024 + pidx) * 16) * 128 + io;
  ushort_t* d1 = K1 + ((size_t)(b * 2048 + pos) * 16) * 128 + io;
  ushort_t* d2 = K2 + ((size_t)(b * 4096 + pos) * 16) * 128 + io;
  f32x4 c4 = *(const f32x4*)(cosT + (size_t)pos * 64 + d);
  f32x4 s4 = *(const f32x4*)(sinT + (size_t)pos * 64 + d);
  u16x4 x1 = *(const u16x4*)(s_);
  u16x4 x2 = *(const u16x4*)(s_ + 64);
  u16x4 o1, o2;
#pragma unroll
  for (int k = 0; k < 4; ++k) {
    float a = bf2f(x1[k]), bb = bf2f(x2[k]);
    o1[k] = f2bf(a * c4[k] - bb * s4[k]);
    o2[k] = f2bf(a * s4[k] + bb * c4[k]);
  }
  *(u16x4*)d1 = o1;
  *(u16x4*)(d1 + 64) = o2;
  *(u16x4*)d2 = o1;
  *(u16x4*)(d2 + 64) = o2;
}

// layer2 cache build: K2[2048:4096) = rope(K1[0:2048), pos+2048)  (V copies fused into GEMM)
__global__ __launch_bounds__(256) void layer2_cache(const ushort_t* __restrict__ K1, ushort_t* __restrict__ K2,
                                                    const float* __restrict__ cosT, const float* __restrict__ sinT) {
  rope_body(K1, K2, cosT, sinT, 2048, 0, 4096, 2048, 2048, blockIdx.x);
}

// ---------- flash attention (round-10 proven config: split-KV 2-way, 4 blocks/CU) ----------
__global__ __launch_bounds__(256, 4) void attn_kernel(
    const ushort_t* __restrict__ Qraw, const ushort_t* __restrict__ Kc, const ushort_t* __restrict__ Vc,
    const float* __restrict__ cosT, const float* __restrict__ sinT,
    ushort_t* __restrict__ Opart, float2* __restrict__ Ml, int Lk) {
  __shared__ __align__(16) ushort_t lsK[8192];
  __shared__ __align__(16) ushort_t lsV[8192];
  const float SC2 = 0.1275174366f;  // (1/sqrt(128)) * log2(e)

  int bid = (int)blockIdx.x;
  int swz = (bid & 7) * 128 + (bid >> 3);
  int s = swz & 1;
  int rest = swz >> 1;

  int w = threadIdx.x >> 6, lane = threadIdx.x & 63;
  int bq = rest & 15, h = (rest >> 4) & 15, b = rest >> 8;
  int qt = bq * 4 + w;
  int g = lane >> 4, r = lane & 15;
  int off = Lk - 1024;

  const ushort_t* qbase = Qraw + ((size_t)(b * 1024 + qt * 16 + r) * 16 + h) * 128;
  int pos = qt * 16 + r;
  const float* cb = cosT + (size_t)pos * 64;
  const float* sb = sinT + (size_t)pos * 64;
  bf16x8 qf[4];
#pragma unroll
  for (int c = 0; c < 2; ++c) {
    int d0 = c * 32 + g * 8;
    f32x4 c0 = *(const f32x4*)(cb + d0);
    f32x4 c1 = *(const f32x4*)(cb + d0 + 4);
    f32x4 s0 = *(const f32x4*)(sb + d0);
    f32x4 s1 = *(const f32x4*)(sb + d0 + 4);
    bf16x8 x1 = *(const bf16x8*)(qbase + d0);
    bf16x8 x2 = *(const bf16x8*)(qbase + d0 + 64);
    bf16x8 lo, hi;
#pragma unroll
    for (int k = 0; k < 8; ++k) {
      float cv = (k < 4 ? c0[k] : c1[k - 4]) * SC2;
      float sv = (k < 4 ? s0[k] : s1[k - 4]) * SC2;
      float a = bf2f((ushort_t)x1[k]);
      float bb = bf2f((ushort_t)x2[k]);
      lo[k] = (short)f2bf(a * cv - bb * sv);
      hi[k] = (short)f2bf(a * sv + bb * cv);
    }
    qf[c] = lo; qf[c + 2] = hi;
  }

  int t = threadIdx.x;
  int krow0 = t >> 4,        kc0 = (t & 15) ^ (krow0 & 7);
  int krow1 = (t + 256) >> 4, kc1 = (t & 15) ^ (krow1 & 7);
  const size_t adv = 32 * 2048;
  const size_t adv2 = 2 * adv;
  const ushort_t* srcK0 = Kc + ((size_t)(b * Lk + krow0) * 16 + h) * 128 + kc0 * 8 + s * adv;
  const ushort_t* srcK1 = Kc + ((size_t)(b * Lk + krow1) * 16 + h) * 128 + kc1 * 8 + s * adv;
  int L0 = t, L1 = t + 256;
  int vrow0 = ((L0 >> 3) & 7) * 4 + ((L0 >> 1) & 3), vd0 = (L0 >> 6) * 16 + (L0 & 1) * 8;
  int vrow1 = ((L1 >> 3) & 7) * 4 + ((L1 >> 1) & 3), vd1 = (L1 >> 6) * 16 + (L1 & 1) * 8;
  const ushort_t* srcV0 = Vc + ((size_t)(b * Lk + vrow0) * 16 + h) * 128 + vd0 + s * adv;
  const ushort_t* srcV1 = Vc + ((size_t)(b * Lk + vrow1) * 16 + h) * 128 + vd1 + s * adv;

  auto STAGE = [&](int buf) {
    ushort_t* k0 = lsK + buf * 4096 + w * 512;
    ushort_t* v0 = lsV + buf * 4096 + w * 512;
    gload_lds16(srcK0, k0);
    gload_lds16(srcK1, k0 + 2048);
    gload_lds16(srcV0, v0);
    gload_lds16(srcV1, v0 + 2048);
    srcK0 += adv2; srcK1 += adv2; srcV0 += adv2; srcV1 += adv2;
  };

  unsigned kx[4];
  unsigned kbase0 = ldsaddr(lsK) + (unsigned)(r * 256);
#pragma unroll
  for (int c = 0; c < 4; ++c)
    kx[c] = kbase0 + (unsigned)((((c * 32 + g * 8) ^ ((r & 7) * 8))) * 2);
  unsigned vbase0 = ldsaddr(lsV);

  float m_run = -1e30f, l_run = 0.f;
  f32x4 o[8];
#pragma unroll
  for (int c = 0; c < 8; ++c) o[c] = 0.f;

  int qp = qt * 16 + r + off;
  int qmin = qt * 16 + off;
  int nkt_w = ((qt * 16 + 15 + off) >> 5) + 1;
  int nkt_blk = (((bq * 4 + 3) * 16 + 15 + off) >> 5) + 1;
  int ntile = (nkt_blk - s + 1) >> 1;

#define LDK(c, ks) ldsb128o<(ks) * 4096>(kx[c] + kb)
#define LDV(hh, i) tr16o<(hh) * 4096 + (i) * 512>(vb)

  if (ntile > 0) {
    STAGE(0);
    for (int it = 0; it < ntile; ++it) {
      int kt = s + it * 2;
      int cur = it & 1;
      if (it + 1 < ntile) {
        STAGE(cur ^ 1);
        asm volatile("s_waitcnt vmcnt(4)" ::: "memory");
      } else {
        asm volatile("s_waitcnt vmcnt(0)" ::: "memory");
      }
      __builtin_amdgcn_s_barrier();
      __builtin_amdgcn_sched_barrier(0);
      if (kt < nkt_w) {
        unsigned kb = (unsigned)(cur << 13);
        unsigned vb = vbase0 + kb;
        f32x4 st[2];
        {
          bf16x8 k0 = LDK(0, 0), k1 = LDK(1, 0), k2 = LDK(2, 0), k3 = LDK(3, 0);
          asm volatile("s_waitcnt lgkmcnt(0)" ::: "memory");
          __builtin_amdgcn_sched_barrier(0);
          __builtin_amdgcn_s_setprio(1);
          f32x4 acc = 0.f;
          acc = __builtin_amdgcn_mfma_f32_16x16x32_bf16(k0, qf[0], acc, 0, 0, 0);
          acc = __builtin_amdgcn_mfma_f32_16x16x32_bf16(k1, qf[1], acc, 0, 0, 0);
          acc = __builtin_amdgcn_mfma_f32_16x16x32_bf16(k2, qf[2], acc, 0, 0, 0);
          acc = __builtin_amdgcn_mfma_f32_16x16x32_bf16(k3, qf[3], acc, 0, 0, 0);
          __builtin_amdgcn_s_setprio(0);
          st[0] = acc;
        }
        {
          bf16x8 k0 = LDK(0, 1), k1 = LDK(1, 1), k2 = LDK(2, 1), k3 = LDK(3, 1);
          asm volatile("s_waitcnt lgkmcnt(0)" ::: "memory");
          __builtin_amdgcn_sched_barrier(0);
          __builtin_amdgcn_s_setprio(1);
          f32x4 acc = 0.f;
          acc = __builtin_amdgcn_mfma_f32_16x16x32_bf16(k0, qf[0], acc, 0, 0, 0);
          acc = __builtin_amdgcn_mfma_f32_16x16x32_bf16(k1, qf[1], acc, 0, 0, 0);
          acc = __builtin_amdgcn_mfma_f32_16x16x32_bf16(k2, qf[2], acc, 0, 0, 0);
          acc = __builtin_amdgcn_mfma_f32_16x16x32_bf16(k3, qf[3], acc, 0, 0, 0);
          __builtin_amdgcn_s_setprio(0);
          st[1] = acc;
        }
        // softmax (log2 domain)
        float pmaxl = -1e30f;
        int kp0 = kt * 32;
        if (kp0 + 31 > qmin) {
#pragma unroll
          for (int ks = 0; ks < 2; ++ks)
#pragma unroll
            for (int j = 0; j < 4; ++j) {
              int key = kp0 + ks * 16 + g * 4 + j;
              float sv = st[ks][j];
              if (key > qp) sv = -1e30f;
              st[ks][j] = sv;
              pmaxl = fmaxf(pmaxl, sv);
            }
        } else {
#pragma unroll
          for (int ks = 0; ks < 2; ++ks)
#pragma unroll
            for (int j = 0; j < 4; ++j) pmaxl = fmaxf(pmaxl, st[ks][j]);
        }
        if (!__all(pmaxl <= m_run + 11.5f)) {
          float pmax = fmaxf(pmaxl, __shfl_xor(pmaxl, 16, 64));
          pmax = fmaxf(pmax, __shfl_xor(pmax, 32, 64));
          if (pmax > m_run + 11.5f) {
            float mnew = fmaxf(m_run, pmax);
            float corr = exp2f(m_run - mnew);
            l_run *= corr;
#pragma unroll
            for (int c = 0; c < 8; ++c)
#pragma unroll
              for (int tt = 0; tt < 4; ++tt) o[c][tt] *= corr;
            m_run = mnew;
          }
        }
        float psum = 0.f;
        bf16x4 pf[2];
#pragma unroll
        for (int ks = 0; ks < 2; ++ks)
#pragma unroll
          for (int j = 0; j < 4; ++j) {
            float pe = exp2f(st[ks][j] - m_run);
            psum += pe;
            pf[ks][j] = (short)f2bf(pe);
          }
        psum += __shfl_xor(psum, 16, 64);
        psum += __shfl_xor(psum, 32, 64);
        l_run += psum;
        {
          bf16x4 v0 = LDV(0, 0), v1 = LDV(0, 1), v2 = LDV(0, 2), v3 = LDV(0, 3);
          bf16x4 v4 = LDV(0, 4), v5 = LDV(0, 5), v6 = LDV(0, 6), v7 = LDV(0, 7);
          asm volatile("s_waitcnt lgkmcnt(0)" ::: "memory");
          __builtin_amdgcn_sched_barrier(0);
          __builtin_amdgcn_s_setprio(1);
          o[0] = __builtin_amdgcn_mfma_f32_16x16x16bf16_1k(v0, pf[0], o[0], 0, 0, 0);
          o[0] = __builtin_amdgcn_mfma_f32_16x16x16bf16_1k(v1, pf[1], o[0], 0, 0, 0);
          o[1] = __builtin_amdgcn_mfma_f32_16x16x16bf16_1k(v2, pf[0], o[1], 0, 0, 0);
          o[1] = __builtin_amdgcn_mfma_f32_16x16x16bf16_1k(v3, pf[1], o[1], 0, 0, 0);
          o[2] = __builtin_amdgcn_mfma_f32_16x16x16bf16_1k(v4, pf[0], o[2], 0, 0, 0);
          o[2] = __builtin_amdgcn_mfma_f32_16x16x16bf16_1k(v5, pf[1], o[2], 0, 0, 0);
          o[3] = __builtin_amdgcn_mfma_f32_16x16x16bf16_1k(v6, pf[0], o[3], 0, 0, 0);
          o[3] = __builtin_amdgcn_mfma_f32_16x16x16bf16_1k(v7, pf[1], o[3], 0, 0, 0);
          __builtin_amdgcn_s_setprio(0);
        }
        {
          bf16x4 v0 = LDV(1, 0), v1 = LDV(1, 1), v2 = LDV(1, 2), v3 = LDV(1, 3);
          bf16x4 v4 = LDV(1, 4), v5 = LDV(1, 5), v6 = LDV(1, 6), v7 = LDV(1, 7);
          asm volatile("s_waitcnt lgkmcnt(0)" ::: "memory");
          __builtin_amdgcn_sched_barrier(0);
          __builtin_amdgcn_s_setprio(1);
          o[4] = __builtin_amdgcn_mfma_f32_16x16x16bf16_1k(v0, pf[0], o[4], 0, 0, 0);
          o[4] = __builtin_amdgcn_mfma_f32_16x16x16bf16_1k(v1, pf[1], o[4], 0, 0, 0);
          o[5] = __builtin_amdgcn_mfma_f32_16x16x16bf16_1k(v2, pf[0], o[5], 0, 0, 0);
          o[5] = __builtin_amdgcn_mfma_f32_16x16x16bf16_1k(v3, pf[1], o[5], 0, 0, 0);
          o[6] = __builtin_amdgcn_mfma_f32_16x16x16bf16_1k(v4, pf[0], o[6], 0, 0, 0);
          o[6] = __builtin_amdgcn_mfma_f32_16x16x16bf16_1k(v5, pf[1], o[6], 0, 0, 0);
          o[7] = __builtin_amdgcn_mfma_f32_16x16x16bf16_1k(v6, pf[0], o[7], 0, 0, 0);
          o[7] = __builtin_amdgcn_mfma_f32_16x16x16bf16_1k(v7, pf[1], o[7], 0, 0, 0);
          __builtin_amdgcn_s_setprio(0);
        }
      }
      __builtin_amdgcn_sched_barrier(0);
      __builtin_amdgcn_s_barrier();
    }
  }
#undef LDK
#undef LDV
  ushort_t* ob = Opart + (size_t)s * 4194304 + ((size_t)(b * 1024 + qt * 16 + r) * 16 + h) * 128;
#pragma unroll
  for (int dblk = 0; dblk < 8; ++dblk) {
    u16x4 ov;
#pragma unroll
    for (int tt = 0; tt < 4; ++tt) ov[tt] = f2bf(o[dblk][tt]);
    *(u16x4*)(ob + dblk * 16 + g * 4) = ov;
  }
  if (g == 0) {
    float2 ml; ml.x = m_run; ml.y = l_run;
    Ml[((size_t)(s * 2 + b) * 1024 + qt * 16 + r) * 16 + h] = ml;
  }
}

// ---------- combine 2 split partials (bf16, log2-domain m) + RMS norm + accumulate ----------
template <int FIRST>
__global__ __launch_bounds__(256) void rms_combine(const ushort_t* __restrict__ Opart, const float2* __restrict__ Ml,
                                                   const float* __restrict__ lnw, const float* __restrict__ lam,
                                                   int li, float* __restrict__ total) {
  int row = blockIdx.x;
  int t8 = threadIdx.x * 8;
  int h = t8 >> 7;
  float2 ml0 = Ml[(size_t)row * 16 + h];
  float2 ml1 = Ml[(size_t)(row + 2048) * 16 + h];
  float M = fmaxf(ml0.x, ml1.x);
  float w0 = exp2f(ml0.x - M), w1 = exp2f(ml1.x - M);
  float rinv = 1.f / (w0 * ml0.y + w1 * ml1.y);
  w0 *= rinv; w1 *= rinv;
  const ushort_t* a0 = Opart + (size_t)row * 2048 + t8;
  const ushort_t* a1 = a0 + 4194304;
  u16x4 p00 = *(const u16x4*)(a0);
  u16x4 p01 = *(const u16x4*)(a0 + 4);
  u16x4 p10 = *(const u16x4*)(a1);
  u16x4 p11 = *(const u16x4*)(a1 + 4);
  f32x4 v0, v1;
#pragma unroll
  for (int k = 0; k < 4; ++k) {
    v0[k] = w0 * bf2f(p00[k]) + w1 * bf2f(p10[k]);
    v1[k] = w0 * bf2f(p01[k]) + w1 * bf2f(p11[k]);
  }
  float ss = v0.x * v0.x + v0.y * v0.y + v0.z * v0.z + v0.w * v0.w +
             v1.x * v1.x + v1.y * v1.y + v1.z * v1.z + v1.w * v1.w;
#pragma unroll
  for (int m = 1; m < 64; m <<= 1) ss += __shfl_xor(ss, m, 64);
  __shared__ float red[4];
  int w = threadIdx.x >> 6, lane = threadIdx.x & 63;
  if (lane == 0) red[w] = ss;
  __syncthreads();
  ss = red[0] + red[1] + red[2] + red[3];
  float sca = rsqrtf(ss * (1.f / 2048.f) + 1e-5f) * lam[li];
  f32x4 w0v = *(const f32x4*)(lnw + t8);
  f32x4 w1v = *(const f32x4*)(lnw + t8 + 4);
  float* o = total + (size_t)row * 2048 + t8;
  f32x4 r0, r1;
#pragma unroll
  for (int k = 0; k < 4; ++k) { r0[k] = v0[k] * sca * w0v[k]; r1[k] = v1[k] * sca * w1v[k]; }
  if (!FIRST) {
    f32x4 q0 = *(const f32x4*)(o);
    f32x4 q1 = *(const f32x4*)(o + 4);
#pragma unroll
    for (int k = 0; k < 4; ++k) { r0[k] += q0[k]; r1[k] += q1[k]; }
  }
  *(f32x4*)(o) = r0;
  *(f32x4*)(o + 4) = r1;
}

// ---------- final: y = rms(total + alpha*x)*flw -> bf16 ----------
__global__ __launch_bounds__(256) void final_norm(const float* __restrict__ total, const float* __restrict__ x,
                                                  const float* __restrict__ alphap, const float* __restrict__ flw,
                                                  ushort_t* __restrict__ ybf) {
  int row = blockIdx.x;
  float al = alphap[0];
  int t8 = threadIdx.x * 8;
  const float* tp = total + (size_t)row * 2048 + t8;
  const float* xp = x + (size_t)row * 2048 + t8;
  f32x4 t0 = *(const f32x4*)(tp);
  f32x4 t1 = *(const f32x4*)(tp + 4);
  f32x4 x0 = *(const f32x4*)(xp);
  f32x4 x1 = *(const f32x4*)(xp + 4);
  float y[8];
#pragma unroll
  for (int k = 0; k < 4; ++k) { y[k] = t0[k] + al * x0[k]; y[4 + k] = t1[k] + al * x1[k]; }
  float ss = 0.f;
#pragma unroll
  for (int k = 0; k < 8; ++k) ss += y[k] * y[k];
#pragma unroll
  for (int m = 1; m < 64; m <<= 1) ss += __shfl_xor(ss, m, 64);
  __shared__ float red[4];
  int w = threadIdx.x >> 6, lane = threadIdx.x & 63;
  if (lane == 0) red[w] = ss;
  __syncthreads();
  ss = red[0] + red[1] + red[2] + red[3];
  float s = rsqrtf(ss * (1.f / 2048.f) + 1e-5f);
  f32x4 w0 = *(const f32x4*)(flw + t8);
  f32x4 w1 = *(const f32x4*)(flw + t8 + 4);
  u16x4 o0, o1;
#pragma unroll
  for (int k = 0; k < 4; ++k) {
    o0[k] = f2bf(y[k] * s * w0[k]);
    o1[k] = f2bf(y[4 + k] * s * w1[k]);
  }
  *(u16x4*)(ybf + (size_t)row * 2048 + t8) = o0;
  *(u16x4*)(ybf + (size_t)row * 2048 + t8 + 4) = o1;
}

// ---------- host ----------
extern "C" void kernel_launch(void* const* d_in, const int* in_sizes, int n_in,
                              void* d_out, int out_size, void* d_ws, size_t ws_size,
                              hipStream_t stream) {
  const float* x = (const float*)d_in[0];
  const float* cosT = (const float*)d_in[1];
  const float* sinT = (const float*)d_in[2];
  const float* wq = (const float*)d_in[3];
  const float* wk = (const float*)d_in[4];
  const float* wv = (const float*)d_in[5];
  const float* lnw = (const float*)d_in[6];
  const float* lambdas = (const float*)d_in[7];
  const float* w_out = (const float*)d_in[8];
  const float* flw = (const float*)d_in[9];
  const float* alpha = (const float*)d_in[10];

  const size_t ME = 4194304ull;
  char* p = (char*)d_ws;
  size_t off = 0;
  auto alc = [&](size_t bytes) -> void* {
    void* r = p + off;
    off += (bytes + 255) & ~(size_t)255;
    return r;
  };
  ushort_t* xb = (ushort_t*)alc(ME * 2);
  void* uni = alc(2 * ME * 4);                // 32 MB union: wl(24) / Opart-bf16(16) / Ppart(32)
  ushort_t* wl = (ushort_t*)uni;
  ushort_t* Opart = (ushort_t*)uni;
  float* Ppart = (float*)uni;
  ushort_t* q = (ushort_t*)alc(ME * 2);
  ushort_t* K0 = (ushort_t*)alc(ME * 2);
  ushort_t* K1 = (ushort_t*)alc(2 * ME * 2);
  ushort_t* K2 = (ushort_t*)alc(4 * ME * 2);
  ushort_t* V0 = (ushort_t*)alc(ME * 2);
  ushort_t* V1 = (ushort_t*)alc(2 * ME * 2);
  ushort_t* V2 = (ushort_t*)alc(4 * ME * 2);
  float* total = (float*)alc(ME * 4);
  float2* Ml = (float2*)alc(65536 * 8);
  float* lam = (float*)alc(256);
  ushort_t* ybf = q;
  ushort_t* wob = K0;

  f2b_kernel<<<4096, 256, 0, stream>>>(x, xb, 4194304);
  lam_kernel<<<1, 64, 0, stream>>>(lambdas, lam);

  ushort_t* Kc[3] = {K0, K1, K2};
  ushort_t* Vc[3] = {V0, V1, V2};
  const size_t S2 = (size_t)2048 * 2048;   // V1 batch stride (elements)
  const size_t S4 = (size_t)4096 * 2048;   // V2 batch stride

  for (int li = 0; li < 3; ++li) {
    int L = 1024 << li;
    size_t woff = (size_t)li * ME;
    f2b3_kernel<<<12288, 256, 0, stream>>>(wq + woff, wk + woff, wv + woff, wl);
    // V replication targets (fused cache copies):
    ushort_t *ve0 = nullptr, *ve1 = nullptr, *ve2 = nullptr;
    size_t vs0 = 0, vs1 = 0, vs2 = 0;
    if (li == 0) {
      ve0 = V1 + (size_t)1024 * 2048; vs0 = S2;   // v0 -> V1[1024:2048)
      ve1 = V2 + (size_t)1024 * 2048; vs1 = S4;   // v0 -> V2[1024:2048)
      ve2 = V2 + (size_t)3072 * 2048; vs2 = S4;   // v0 -> V2[3072:4096)
    } else if (li == 1) {
      ve0 = V2 + (size_t)2048 * 2048; vs0 = S4;   // v1 -> V2[2048:3072)
    }
    gemm_qkv256<<<192, 512, 0, stream>>>(xb, wl, wl + ME, wl + 2 * ME,
                                         q, Kc[li], Vc[li], L,
                                         ve0, vs0, ve1, vs1, ve2, vs2);
    rope_k<<<2048, 256, 0, stream>>>(Kc[li], cosT, sinT, L);
    if (li == 1)
      layer1_cache<<<2048, 256, 0, stream>>>(K0, K1, K2, cosT, sinT);
    else if (li == 2)
      layer2_cache<<<4096, 256, 0, stream>>>(K1, K2, cosT, sinT);
    attn_kernel<<<1024, 256, 0, stream>>>(q, Kc[li], Vc[li], cosT, sinT, Opart, Ml, L);
    if (li == 0)
      rms_combine<1><<<2048, 256, 0, stream>>>(Opart, Ml, lnw, lam, 0, total);
    else
      rms_combine<0><<<2048, 256, 0, stream>>>(Opart, Ml, lnw + (size_t)li * 2048, lam, li, total);
  }

  f2b_kernel<<<4096, 256, 0, stream>>>(w_out, wob, 4194304);
  final_norm<<<2048, 256, 0, stream>>>(total, x, alpha, flw, ybf);
  gemm_bt_part<<<dim3(16, 16, 2), 256, 0, stream>>>(ybf, wob, Ppart);
  add2_kernel<<<4096, 256, 0, stream>>>(Ppart, Ppart + ME, (float*)d_out);
}

// Round 13
// 541.306 us; speedup vs baseline: 1.5673x; 1.0260x over previous
//
#include <hip/hip_runtime.h>
#include <hip/hip_bf16.h>

typedef unsigned short ushort_t;
typedef __attribute__((ext_vector_type(8))) short bf16x8;
typedef __attribute__((ext_vector_type(4))) short bf16x4;
typedef __attribute__((ext_vector_type(4))) float f32x4;
typedef __attribute__((ext_vector_type(4))) unsigned short u16x4;
typedef __attribute__((ext_vector_type(4))) unsigned int u32x4;

#define DEV __device__ __forceinline__

// ---------- helpers ----------
DEV ushort_t f2bf(float f) {
  __hip_bfloat16 h = __float2bfloat16(f);   // hardware RNE convert
  return __builtin_bit_cast(unsigned short, h);
}
DEV float bf2f(ushort_t b) {
  union { float f; unsigned int u; } a; a.u = ((unsigned int)b) << 16;
  return a.f;
}
DEV void gload_lds16(const void* g, void* l) {
  __builtin_amdgcn_global_load_lds((const __attribute__((address_space(1))) void*)g,
                                   (__attribute__((address_space(3))) void*)l, 16, 0, 0);
}
DEV unsigned ldsaddr(const void* l) {
  return (unsigned)(unsigned long long)(const __attribute__((address_space(3))) void*)l;
}
template <int OFF>
DEV bf16x4 tr16o(unsigned a) {
  bf16x4 d;
  asm volatile("ds_read_b64_tr_b16 %0, %1 offset:%c2" : "=v"(d) : "v"(a), "i"(OFF));
  return d;
}
template <int OFF>
DEV bf16x8 ldsb128o(unsigned a) {
  bf16x8 d;
  asm volatile("ds_read_b128 %0, %1 offset:%c2" : "=v"(d) : "v"(a), "i"(OFF));
  return d;
}

// ---------- f32 -> bf16 convert ----------
__global__ __launch_bounds__(256) void f2b_kernel(const float* __restrict__ in,
                                                  ushort_t* __restrict__ out, int n) {
  int base = (blockIdx.x * 256 + threadIdx.x) * 4;
  if (base >= n) return;
  f32x4 v = *(const f32x4*)(in + base);
  u16x4 o;
  o.x = f2bf(v.x); o.y = f2bf(v.y); o.z = f2bf(v.z); o.w = f2bf(v.w);
  *(u16x4*)(out + base) = o;
}

// fused 3-tensor convert (per-layer wq/wk/wv)
__global__ __launch_bounds__(256) void f2b3_kernel(const float* __restrict__ a, const float* __restrict__ b,
                                                   const float* __restrict__ c, ushort_t* __restrict__ out) {
  int id = blockIdx.x * 256 + threadIdx.x;
  int sel = id >> 20, k = (id & 1048575) * 4;
  const float* src = sel == 0 ? a : sel == 1 ? b : c;
  f32x4 v = *(const f32x4*)(src + k);
  u16x4 o;
  o.x = f2bf(v.x); o.y = f2bf(v.y); o.z = f2bf(v.z); o.w = f2bf(v.w);
  *(u16x4*)(out + (size_t)sel * 4194304 + k) = o;
}

// ---------- lambda weights ----------
__global__ void lam_kernel(const float* __restrict__ lambdas, float* __restrict__ lam) {
  if (threadIdx.x == 0 && blockIdx.x == 0) {
    float l0 = 1.f / (1.f + __expf(-lambdas[0]));
    float l1 = 1.f / (1.f + __expf(-lambdas[1]));
    float l2 = 1.f / (1.f + __expf(-lambdas[2]));
    float mean = (l0 + l1 + l2) * (1.f / 3.f);
    float d0 = l0 - mean, d1 = l1 - mean, d2 = l2 - mean;
    float var = (d0 * d0 + d1 * d1 + d2 * d2) * (1.f / 3.f);
    float rs = rsqrtf(var + 1e-5f);
    lam[0] = d0 * rs; lam[1] = d1 * rs; lam[2] = d2 * rs;
  }
}

// ---------- legacy 128x128 GEMM core (final projection) ----------
DEV void gemm_core(const ushort_t* __restrict__ A, const ushort_t* __restrict__ Bm,
                   ushort_t* lsA, ushort_t* lsB, int bm, int bn, int kbeg, int kend,
                   f32x4 (&acc)[4][4]) {
  const int K = 2048;
  int tid = threadIdx.x;
  int w = tid >> 6, lane = tid & 63;
  int g = lane >> 4, r = lane & 15;
  int wm = w >> 1, wn = w & 1;
#pragma unroll
  for (int i = 0; i < 4; ++i)
#pragma unroll
    for (int j = 0; j < 4; ++j) acc[i][j] = 0.f;

  for (int kk = kbeg; kk < kend; kk += 32) {
    __syncthreads();
#pragma unroll
    for (int j2 = 0; j2 < 2; ++j2) {
      int eb = w * 1024 + j2 * 512;
      int ebl = eb + lane * 8;
      int rr = ebl >> 5, cc = ebl & 31;
      gload_lds16(A + (size_t)(bm * 128 + rr) * K + kk + cc, lsA + eb);
      gload_lds16(Bm + (size_t)(bn * 128 + rr) * K + kk + cc, lsB + eb);
    }
    __syncthreads();
    bf16x8 af[4], bfr[4];
#pragma unroll
    for (int i = 0; i < 4; ++i)
      af[i] = *(const bf16x8*)(lsA + (wm * 64 + i * 16 + r) * 32 + g * 8);
#pragma unroll
    for (int j = 0; j < 4; ++j)
      bfr[j] = *(const bf16x8*)(lsB + (wn * 64 + j * 16 + r) * 32 + g * 8);
#pragma unroll
    for (int i = 0; i < 4; ++i)
#pragma unroll
      for (int j = 0; j < 4; ++j)
        acc[i][j] = __builtin_amdgcn_mfma_f32_16x16x32_bf16(af[i], bfr[j], acc[i][j], 0, 0, 0);
  }
}

// ---------- 8-phase 256x256 fused QKV GEMM (round-10 proven, clean epilogue) ----------
#define MM(i, j)                                                                              \
  acc[i][j] = __builtin_amdgcn_mfma_f32_16x16x32_bf16(af[(i) & 3][0], bfr[j][0], acc[i][j], 0, 0, 0); \
  acc[i][j] = __builtin_amdgcn_mfma_f32_16x16x32_bf16(af[(i) & 3][1], bfr[j][1], acc[i][j], 0, 0, 0);

__global__ __launch_bounds__(512, 2) void gemm_qkv256(
    const ushort_t* __restrict__ A,
    const ushort_t* __restrict__ Bq, const ushort_t* __restrict__ Bk, const ushort_t* __restrict__ Bv,
    ushort_t* __restrict__ Cq, ushort_t* __restrict__ Ck, ushort_t* __restrict__ Cv, int Lkv) {
  __shared__ __align__(16) ushort_t lsA[32768];
  __shared__ __align__(16) ushort_t lsB[32768];
  const int NT = 32;

  int bid = (int)blockIdx.x;
  int swz = (bid & 7) * 24 + (bid >> 3);
  int bm = swz / 24;
  int rest = swz % 24;
  int sel = rest >> 3, bnc = rest & 7;
  const ushort_t* Bmat = (sel == 0) ? Bq : (sel == 1) ? Bk : Bv;
  ushort_t* C = (sel == 0) ? Cq : (sel == 1) ? Ck : Cv;
  int Lsel = (sel == 0) ? 1024 : Lkv;

  int tid = threadIdx.x;
  int wv = tid >> 6, lane = tid & 63;
  int wm = wv >> 2, wn = wv & 3;
  int g = lane >> 4, r = lane & 15;

  int row0 = tid >> 3, c0 = tid & 7;
  int colsw = (c0 ^ (row0 & 7)) * 8;
  const ushort_t* pA0 = A + (size_t)(bm * 256 + row0) * 2048 + colsw;
  const ushort_t* pB0 = Bmat + (size_t)(bnc * 256 + row0) * 2048 + colsw;
  ushort_t* dA = lsA + tid * 8;
  ushort_t* dB = lsB + tid * 8;

  auto SA = [&](int T, int hh) {
    const ushort_t* s = pA0 + (size_t)(hh * 128) * 2048 + (size_t)T * 64;
    ushort_t* d = dA + (T & 1) * 16384 + hh * 8192;
    gload_lds16(s, d);
    gload_lds16(s + (size_t)64 * 2048, d + 4096);
  };
  auto SB = [&](int T, int hh) {
    const ushort_t* s = pB0 + (size_t)(hh * 128) * 2048 + (size_t)T * 64;
    ushort_t* d = dB + (T & 1) * 16384 + hh * 8192;
    gload_lds16(s, d);
    gload_lds16(s + (size_t)64 * 2048, d + 4096);
  };

  unsigned xm = (unsigned)(r & 7);
  unsigned aAb = ldsaddr(lsA) + (unsigned)((wm * 128 + r) * 128);
  unsigned aA0b = aAb + ((((unsigned)g) ^ xm) << 4);
  unsigned aA1b = aAb + ((((unsigned)(4 + g)) ^ xm) << 4);
  unsigned aBb = ldsaddr(lsB) + (unsigned)((wn * 64 + r) * 128);
  unsigned aB0b = aBb + ((((unsigned)g) ^ xm) << 4);
  unsigned aB1b = aBb + ((((unsigned)(4 + g)) ^ xm) << 4);

  f32x4 acc[8][4];
#pragma unroll
  for (int i = 0; i < 8; ++i)
#pragma unroll
    for (int j = 0; j < 4; ++j) acc[i][j] = 0.f;
  bf16x8 af[4][2], bfr[4][2];

  SA(0, 0); SB(0, 0); SB(0, 1); SA(0, 1);
  SA(1, 0); SB(1, 0); SB(1, 1);
  asm volatile("s_waitcnt vmcnt(6)" ::: "memory");
  __builtin_amdgcn_s_barrier();
  __builtin_amdgcn_sched_barrier(0);

  for (int t = 0; t < NT; ++t) {
    unsigned cb = (unsigned)((t & 1) << 15);
    unsigned A0 = aA0b + cb, A1 = aA1b + cb, B0 = aB0b + cb, B1 = aB1b + cb;
    bool full = (t < NT - 2);
    // phase 0
    af[0][0] = ldsb128o<0>(A0);     af[0][1] = ldsb128o<0>(A1);
    af[1][0] = ldsb128o<2048>(A0);  af[1][1] = ldsb128o<2048>(A1);
    af[2][0] = ldsb128o<4096>(A0);  af[2][1] = ldsb128o<4096>(A1);
    af[3][0] = ldsb128o<6144>(A0);  af[3][1] = ldsb128o<6144>(A1);
    bfr[0][0] = ldsb128o<0>(B0);    bfr[0][1] = ldsb128o<0>(B1);
    bfr[1][0] = ldsb128o<2048>(B0); bfr[1][1] = ldsb128o<2048>(B1);
    if (t + 1 < NT) SA(t + 1, 1);
    __builtin_amdgcn_s_barrier();
    asm volatile("s_waitcnt lgkmcnt(0)" ::: "memory");
    __builtin_amdgcn_sched_barrier(0);
    __builtin_amdgcn_s_setprio(1);
    MM(0, 0) MM(1, 0) MM(2, 0) MM(3, 0) MM(0, 1) MM(1, 1) MM(2, 1) MM(3, 1)
    __builtin_amdgcn_s_setprio(0);
    __builtin_amdgcn_sched_barrier(0);
    __builtin_amdgcn_s_barrier();
    // phase 1
    bfr[2][0] = ldsb128o<4096>(B0); bfr[2][1] = ldsb128o<4096>(B1);
    bfr[3][0] = ldsb128o<6144>(B0); bfr[3][1] = ldsb128o<6144>(B1);
    if (full) SA(t + 2, 0);
    __builtin_amdgcn_s_barrier();
    asm volatile("s_waitcnt lgkmcnt(0)" ::: "memory");
    __builtin_amdgcn_sched_barrier(0);
    __builtin_amdgcn_s_setprio(1);
    MM(0, 2) MM(1, 2) MM(2, 2) MM(3, 2) MM(0, 3) MM(1, 3) MM(2, 3) MM(3, 3)
    __builtin_amdgcn_s_setprio(0);
    if (full) { asm volatile("s_waitcnt vmcnt(4)" ::: "memory"); }
    else      { asm volatile("s_waitcnt vmcnt(0)" ::: "memory"); }
    __builtin_amdgcn_sched_barrier(0);
    __builtin_amdgcn_s_barrier();
    // phase 2
    af[0][0] = ldsb128o<8192>(A0);  af[0][1] = ldsb128o<8192>(A1);
    af[1][0] = ldsb128o<10240>(A0); af[1][1] = ldsb128o<10240>(A1);
    af[2][0] = ldsb128o<12288>(A0); af[2][1] = ldsb128o<12288>(A1);
    af[3][0] = ldsb128o<14336>(A0); af[3][1] = ldsb128o<14336>(A1);
    if (full) SB(t + 2, 0);
    __builtin_amdgcn_s_barrier();
    asm volatile("s_waitcnt lgkmcnt(0)" ::: "memory");
    __builtin_amdgcn_sched_barrier(0);
    __builtin_amdgcn_s_setprio(1);
    MM(4, 2) MM(5, 2) MM(6, 2) MM(7, 2) MM(4, 3) MM(5, 3) MM(6, 3) MM(7, 3)
    __builtin_amdgcn_s_setprio(0);
    __builtin_amdgcn_sched_barrier(0);
    __builtin_amdgcn_s_barrier();
    // phase 3
    if (full) SB(t + 2, 1);
    __builtin_amdgcn_s_barrier();
    __builtin_amdgcn_s_setprio(1);
    MM(4, 0) MM(5, 0) MM(6, 0) MM(7, 0) MM(4, 1) MM(5, 1) MM(6, 1) MM(7, 1)
    __builtin_amdgcn_s_setprio(0);
    if (full) { asm volatile("s_waitcnt vmcnt(8)" ::: "memory"); }
    else      { asm volatile("s_waitcnt vmcnt(0)" ::: "memory"); }
    __builtin_amdgcn_sched_barrier(0);
    __builtin_amdgcn_s_barrier();
  }

  int prow = bm * 256 + wm * 128 + g * 4;
  int pcol = bnc * 256 + wn * 64 + r;
#pragma unroll
  for (int i = 0; i < 8; ++i)
#pragma unroll
    for (int j = 0; j < 4; ++j) {
      int col = pcol + j * 16;
#pragma unroll
      for (int tt = 0; tt < 4; ++tt) {
        int row = prow + i * 16 + tt;
        int b2 = row >> 10, t2 = row & 1023;
        C[(size_t)(b2 * Lsel + t2) * 2048 + col] = f2bf(acc[i][j][tt]);
      }
    }
}
#undef MM

// K-split partial GEMM (final projection)
__global__ __launch_bounds__(256) void gemm_bt_part(
    const ushort_t* __restrict__ A, const ushort_t* __restrict__ Bm, float* __restrict__ P) {
  __shared__ __align__(16) ushort_t lsA[4096];
  __shared__ __align__(16) ushort_t lsB[4096];
  int bn = blockIdx.x, bm = blockIdx.y, s = blockIdx.z;
  f32x4 acc[4][4];
  gemm_core(A, Bm, lsA, lsB, bm, bn, s * 1024, (s + 1) * 1024, acc);
  float* C = P + (size_t)s * 4194304;
  int lane = threadIdx.x & 63, w = threadIdx.x >> 6;
  int g = lane >> 4, r = lane & 15, wm = w >> 1, wn = w & 1;
#pragma unroll
  for (int i = 0; i < 4; ++i)
#pragma unroll
    for (int j = 0; j < 4; ++j) {
      int row0 = bm * 128 + wm * 64 + i * 16 + g * 4;
      int col = bn * 128 + wn * 64 + j * 16 + r;
#pragma unroll
      for (int t = 0; t < 4; ++t)
        C[(size_t)(row0 + t) * 2048 + col] = acc[i][j][t];
    }
}

__global__ __launch_bounds__(256) void add2_kernel(const float* __restrict__ a, const float* __restrict__ b,
                                                   float* __restrict__ out) {
  int i = (blockIdx.x * 256 + threadIdx.x) * 4;
  f32x4 va = *(const f32x4*)(a + i);
  f32x4 vb = *(const f32x4*)(b + i);
  f32x4 r;
#pragma unroll
  for (int k = 0; k < 4; ++k) r[k] = va[k] + vb[k];
  *(f32x4*)(out + i) = r;
}

// ---------- rope / copy bodies ----------
DEV void rope_body(const ushort_t* src, ushort_t* dst, const float* cosT, const float* sinT,
                   int Ls, int s0, int Ld, int dpos0, int cnt, int bp) {
  int b = bp / cnt, pidx = bp % cnt;
  int pos = dpos0 + pidx;
  int pi = threadIdx.x * 4;
  int h = pi >> 6, d = pi & 63;
  const ushort_t* s_ = src + ((size_t)(b * Ls + s0 + pidx) * 16 + h) * 128 + d;
  ushort_t* d_ = dst + ((size_t)(b * Ld + pos) * 16 + h) * 128 + d;
  f32x4 c4 = *(const f32x4*)(cosT + (size_t)pos * 64 + d);
  f32x4 s4 = *(const f32x4*)(sinT + (size_t)pos * 64 + d);
  u16x4 x1 = *(const u16x4*)(s_);
  u16x4 x2 = *(const u16x4*)(s_ + 64);
  u16x4 o1, o2;
#pragma unroll
  for (int k = 0; k < 4; ++k) {
    float a = bf2f(x1[k]), bb = bf2f(x2[k]);
    o1[k] = f2bf(a * c4[k] - bb * s4[k]);
    o2[k] = f2bf(a * s4[k] + bb * c4[k]);
  }
  *(u16x4*)d_ = o1;
  *(u16x4*)(d_ + 64) = o2;
}
DEV void copy_body(const ushort_t* src, ushort_t* dst, int Ls, int s0, int Ld, int dpos0,
                   int cnt, int bp) {
  int b = bp / cnt, pidx = bp % cnt;
  const u32x4* s = (const u32x4*)(src + (size_t)(b * Ls + s0 + pidx) * 2048);
  u32x4* d = (u32x4*)(dst + (size_t)(b * Ld + dpos0 + pidx) * 2048);
  d[threadIdx.x] = s[threadIdx.x];
}

__global__ __launch_bounds__(256) void rope_k(ushort_t* Kc, const float* __restrict__ cosT,
                                              const float* __restrict__ sinT, int L) {
  rope_body(Kc, Kc, cosT, sinT, L, 0, L, 0, 1024, blockIdx.x);
}

// layer1 cache build: K1[1024:2048) = K2[1024:2048) = rope(K0, pos+1024) (dual-dest);
// V1[1024:2048) = V0
__global__ __launch_bounds__(256) void layer1_cache(const ushort_t* __restrict__ K0, ushort_t* __restrict__ K1,
                                                    ushort_t* __restrict__ K2,
                                                    const ushort_t* __restrict__ V0, ushort_t* __restrict__ V1,
                                                    const float* __restrict__ cosT, const float* __restrict__ sinT) {
  int bp = blockIdx.x;
  if (bp < 2048) {
    int b = bp >> 10, pidx = bp & 1023;
    int pos = 1024 + pidx;
    int pi = threadIdx.x * 4;
    int h = pi >> 6, d = pi & 63;
    size_t io = ((size_t)h) * 128 + d;
    const ushort_t* s_ = K0 + ((size_t)(b * 1024 + pidx) * 16) * 128 + io;
    ushort_t* d1 = K1 + ((size_t)(b * 2048 + pos) * 16) * 128 + io;
    ushort_t* d2 = K2 + ((size_t)(b * 4096 + pos) * 16) * 128 + io;
    f32x4 c4 = *(const f32x4*)(cosT + (size_t)pos * 64 + d);
    f32x4 s4 = *(const f32x4*)(sinT + (size_t)pos * 64 + d);
    u16x4 x1 = *(const u16x4*)(s_);
    u16x4 x2 = *(const u16x4*)(s_ + 64);
    u16x4 o1, o2;
#pragma unroll
    for (int k = 0; k < 4; ++k) {
      float a = bf2f(x1[k]), bb = bf2f(x2[k]);
      o1[k] = f2bf(a * c4[k] - bb * s4[k]);
      o2[k] = f2bf(a * s4[k] + bb * c4[k]);
    }
    *(u16x4*)d1 = o1;
    *(u16x4*)(d1 + 64) = o2;
    *(u16x4*)d2 = o1;
    *(u16x4*)(d2 + 64) = o2;
  } else {
    copy_body(V0, V1, 1024, 0, 2048, 1024, 1024, bp - 2048);
  }
}

// layer2 cache build: K2[2048:4096) = rope(K1[0:2048), pos+2048);
// V2[1024:2048) = V1[1024:2048); V2[2048:4096) = V1[0:2048)
__global__ __launch_bounds__(256) void layer2_cache(const ushort_t* __restrict__ K1, ushort_t* __restrict__ K2,
                                                    const ushort_t* __restrict__ V1, ushort_t* __restrict__ V2,
                                                    const float* __restrict__ cosT, const float* __restrict__ sinT) {
  int bp = blockIdx.x;
  if (bp < 4096) rope_body(K1, K2, cosT, sinT, 2048, 0, 4096, 2048, 2048, bp);
  else if (bp < 6144) copy_body(V1, V2, 2048, 1024, 4096, 1024, 1024, bp - 4096);
  else copy_body(V1, V2, 2048, 0, 4096, 2048, 2048, bp - 6144);
}

// ---------- flash attention (round-10 proven config: split-KV 2-way, 4 blocks/CU) ----------
__global__ __launch_bounds__(256, 4) void attn_kernel(
    const ushort_t* __restrict__ Qraw, const ushort_t* __restrict__ Kc, const ushort_t* __restrict__ Vc,
    const float* __restrict__ cosT, const float* __restrict__ sinT,
    ushort_t* __restrict__ Opart, float2* __restrict__ Ml, int Lk) {
  __shared__ __align__(16) ushort_t lsK[8192];
  __shared__ __align__(16) ushort_t lsV[8192];
  const float SC2 = 0.1275174366f;  // (1/sqrt(128)) * log2(e)

  int bid = (int)blockIdx.x;
  int swz = (bid & 7) * 128 + (bid >> 3);
  int s = swz & 1;
  int rest = swz >> 1;

  int w = threadIdx.x >> 6, lane = threadIdx.x & 63;
  int bq = rest & 15, h = (rest >> 4) & 15, b = rest >> 8;
  int qt = bq * 4 + w;
  int g = lane >> 4, r = lane & 15;
  int off = Lk - 1024;

  const ushort_t* qbase = Qraw + ((size_t)(b * 1024 + qt * 16 + r) * 16 + h) * 128;
  int pos = qt * 16 + r;
  const float* cb = cosT + (size_t)pos * 64;
  const float* sb = sinT + (size_t)pos * 64;
  bf16x8 qf[4];
#pragma unroll
  for (int c = 0; c < 2; ++c) {
    int d0 = c * 32 + g * 8;
    f32x4 c0 = *(const f32x4*)(cb + d0);
    f32x4 c1 = *(const f32x4*)(cb + d0 + 4);
    f32x4 s0 = *(const f32x4*)(sb + d0);
    f32x4 s1 = *(const f32x4*)(sb + d0 + 4);
    bf16x8 x1 = *(const bf16x8*)(qbase + d0);
    bf16x8 x2 = *(const bf16x8*)(qbase + d0 + 64);
    bf16x8 lo, hi;
#pragma unroll
    for (int k = 0; k < 8; ++k) {
      float cv = (k < 4 ? c0[k] : c1[k - 4]) * SC2;
      float sv = (k < 4 ? s0[k] : s1[k - 4]) * SC2;
      float a = bf2f((ushort_t)x1[k]);
      float bb = bf2f((ushort_t)x2[k]);
      lo[k] = (short)f2bf(a * cv - bb * sv);
      hi[k] = (short)f2bf(a * sv + bb * cv);
    }
    qf[c] = lo; qf[c + 2] = hi;
  }

  int t = threadIdx.x;
  int krow0 = t >> 4,        kc0 = (t & 15) ^ (krow0 & 7);
  int krow1 = (t + 256) >> 4, kc1 = (t & 15) ^ (krow1 & 7);
  const size_t adv = 32 * 2048;
  const size_t adv2 = 2 * adv;
  const ushort_t* srcK0 = Kc + ((size_t)(b * Lk + krow0) * 16 + h) * 128 + kc0 * 8 + s * adv;
  const ushort_t* srcK1 = Kc + ((size_t)(b * Lk + krow1) * 16 + h) * 128 + kc1 * 8 + s * adv;
  int L0 = t, L1 = t + 256;
  int vrow0 = ((L0 >> 3) & 7) * 4 + ((L0 >> 1) & 3), vd0 = (L0 >> 6) * 16 + (L0 & 1) * 8;
  int vrow1 = ((L1 >> 3) & 7) * 4 + ((L1 >> 1) & 3), vd1 = (L1 >> 6) * 16 + (L1 & 1) * 8;
  const ushort_t* srcV0 = Vc + ((size_t)(b * Lk + vrow0) * 16 + h) * 128 + vd0 + s * adv;
  const ushort_t* srcV1 = Vc + ((size_t)(b * Lk + vrow1) * 16 + h) * 128 + vd1 + s * adv;

  auto STAGE = [&](int buf) {
    ushort_t* k0 = lsK + buf * 4096 + w * 512;
    ushort_t* v0 = lsV + buf * 4096 + w * 512;
    gload_lds16(srcK0, k0);
    gload_lds16(srcK1, k0 + 2048);
    gload_lds16(srcV0, v0);
    gload_lds16(srcV1, v0 + 2048);
    srcK0 += adv2; srcK1 += adv2; srcV0 += adv2; srcV1 += adv2;
  };

  unsigned kx[4];
  unsigned kbase0 = ldsaddr(lsK) + (unsigned)(r * 256);
#pragma unroll
  for (int c = 0; c < 4; ++c)
    kx[c] = kbase0 + (unsigned)((((c * 32 + g * 8) ^ ((r & 7) * 8))) * 2);
  unsigned vbase0 = ldsaddr(lsV);

  float m_run = -1e30f, l_run = 0.f;
  f32x4 o[8];
#pragma unroll
  for (int c = 0; c < 8; ++c) o[c] = 0.f;

  int qp = qt * 16 + r + off;
  int qmin = qt * 16 + off;
  int nkt_w = ((qt * 16 + 15 + off) >> 5) + 1;
  int nkt_blk = (((bq * 4 + 3) * 16 + 15 + off) >> 5) + 1;
  int ntile = (nkt_blk - s + 1) >> 1;

#define LDK(c, ks) ldsb128o<(ks) * 4096>(kx[c] + kb)
#define LDV(hh, i) tr16o<(hh) * 4096 + (i) * 512>(vb)

  if (ntile > 0) {
    STAGE(0);
    for (int it = 0; it < ntile; ++it) {
      int kt = s + it * 2;
      int cur = it & 1;
      if (it + 1 < ntile) {
        STAGE(cur ^ 1);
        asm volatile("s_waitcnt vmcnt(4)" ::: "memory");
      } else {
        asm volatile("s_waitcnt vmcnt(0)" ::: "memory");
      }
      __builtin_amdgcn_s_barrier();
      __builtin_amdgcn_sched_barrier(0);
      if (kt < nkt_w) {
        unsigned kb = (unsigned)(cur << 13);
        unsigned vb = vbase0 + kb;
        f32x4 st[2];
        {
          bf16x8 k0 = LDK(0, 0), k1 = LDK(1, 0), k2 = LDK(2, 0), k3 = LDK(3, 0);
          asm volatile("s_waitcnt lgkmcnt(0)" ::: "memory");
          __builtin_amdgcn_sched_barrier(0);
          __builtin_amdgcn_s_setprio(1);
          f32x4 acc = 0.f;
          acc = __builtin_amdgcn_mfma_f32_16x16x32_bf16(k0, qf[0], acc, 0, 0, 0);
          acc = __builtin_amdgcn_mfma_f32_16x16x32_bf16(k1, qf[1], acc, 0, 0, 0);
          acc = __builtin_amdgcn_mfma_f32_16x16x32_bf16(k2, qf[2], acc, 0, 0, 0);
          acc = __builtin_amdgcn_mfma_f32_16x16x32_bf16(k3, qf[3], acc, 0, 0, 0);
          __builtin_amdgcn_s_setprio(0);
          st[0] = acc;
        }
        {
          bf16x8 k0 = LDK(0, 1), k1 = LDK(1, 1), k2 = LDK(2, 1), k3 = LDK(3, 1);
          asm volatile("s_waitcnt lgkmcnt(0)" ::: "memory");
          __builtin_amdgcn_sched_barrier(0);
          __builtin_amdgcn_s_setprio(1);
          f32x4 acc = 0.f;
          acc = __builtin_amdgcn_mfma_f32_16x16x32_bf16(k0, qf[0], acc, 0, 0, 0);
          acc = __builtin_amdgcn_mfma_f32_16x16x32_bf16(k1, qf[1], acc, 0, 0, 0);
          acc = __builtin_amdgcn_mfma_f32_16x16x32_bf16(k2, qf[2], acc, 0, 0, 0);
          acc = __builtin_amdgcn_mfma_f32_16x16x32_bf16(k3, qf[3], acc, 0, 0, 0);
          __builtin_amdgcn_s_setprio(0);
          st[1] = acc;
        }
        // softmax (log2 domain)
        float pmaxl = -1e30f;
        int kp0 = kt * 32;
        if (kp0 + 31 > qmin) {
#pragma unroll
          for (int ks = 0; ks < 2; ++ks)
#pragma unroll
            for (int j = 0; j < 4; ++j) {
              int key = kp0 + ks * 16 + g * 4 + j;
              float sv = st[ks][j];
              if (key > qp) sv = -1e30f;
              st[ks][j] = sv;
              pmaxl = fmaxf(pmaxl, sv);
            }
        } else {
#pragma unroll
          for (int ks = 0; ks < 2; ++ks)
#pragma unroll
            for (int j = 0; j < 4; ++j) pmaxl = fmaxf(pmaxl, st[ks][j]);
        }
        if (!__all(pmaxl <= m_run + 11.5f)) {
          float pmax = fmaxf(pmaxl, __shfl_xor(pmaxl, 16, 64));
          pmax = fmaxf(pmax, __shfl_xor(pmax, 32, 64));
          if (pmax > m_run + 11.5f) {
            float mnew = fmaxf(m_run, pmax);
            float corr = exp2f(m_run - mnew);
            l_run *= corr;
#pragma unroll
            for (int c = 0; c < 8; ++c)
#pragma unroll
              for (int tt = 0; tt < 4; ++tt) o[c][tt] *= corr;
            m_run = mnew;
          }
        }
        float psum = 0.f;
        bf16x4 pf[2];
#pragma unroll
        for (int ks = 0; ks < 2; ++ks)
#pragma unroll
          for (int j = 0; j < 4; ++j) {
            float pe = exp2f(st[ks][j] - m_run);
            psum += pe;
            pf[ks][j] = (short)f2bf(pe);
          }
        psum += __shfl_xor(psum, 16, 64);
        psum += __shfl_xor(psum, 32, 64);
        l_run += psum;
        {
          bf16x4 v0 = LDV(0, 0), v1 = LDV(0, 1), v2 = LDV(0, 2), v3 = LDV(0, 3);
          bf16x4 v4 = LDV(0, 4), v5 = LDV(0, 5), v6 = LDV(0, 6), v7 = LDV(0, 7);
          asm volatile("s_waitcnt lgkmcnt(0)" ::: "memory");
          __builtin_amdgcn_sched_barrier(0);
          __builtin_amdgcn_s_setprio(1);
          o[0] = __builtin_amdgcn_mfma_f32_16x16x16bf16_1k(v0, pf[0], o[0], 0, 0, 0);
          o[0] = __builtin_amdgcn_mfma_f32_16x16x16bf16_1k(v1, pf[1], o[0], 0, 0, 0);
          o[1] = __builtin_amdgcn_mfma_f32_16x16x16bf16_1k(v2, pf[0], o[1], 0, 0, 0);
          o[1] = __builtin_amdgcn_mfma_f32_16x16x16bf16_1k(v3, pf[1], o[1], 0, 0, 0);
          o[2] = __builtin_amdgcn_mfma_f32_16x16x16bf16_1k(v4, pf[0], o[2], 0, 0, 0);
          o[2] = __builtin_amdgcn_mfma_f32_16x16x16bf16_1k(v5, pf[1], o[2], 0, 0, 0);
          o[3] = __builtin_amdgcn_mfma_f32_16x16x16bf16_1k(v6, pf[0], o[3], 0, 0, 0);
          o[3] = __builtin_amdgcn_mfma_f32_16x16x16bf16_1k(v7, pf[1], o[3], 0, 0, 0);
          __builtin_amdgcn_s_setprio(0);
        }
        {
          bf16x4 v0 = LDV(1, 0), v1 = LDV(1, 1), v2 = LDV(1, 2), v3 = LDV(1, 3);
          bf16x4 v4 = LDV(1, 4), v5 = LDV(1, 5), v6 = LDV(1, 6), v7 = LDV(1, 7);
          asm volatile("s_waitcnt lgkmcnt(0)" ::: "memory");
          __builtin_amdgcn_sched_barrier(0);
          __builtin_amdgcn_s_setprio(1);
          o[4] = __builtin_amdgcn_mfma_f32_16x16x16bf16_1k(v0, pf[0], o[4], 0, 0, 0);
          o[4] = __builtin_amdgcn_mfma_f32_16x16x16bf16_1k(v1, pf[1], o[4], 0, 0, 0);
          o[5] = __builtin_amdgcn_mfma_f32_16x16x16bf16_1k(v2, pf[0], o[5], 0, 0, 0);
          o[5] = __builtin_amdgcn_mfma_f32_16x16x16bf16_1k(v3, pf[1], o[5], 0, 0, 0);
          o[6] = __builtin_amdgcn_mfma_f32_16x16x16bf16_1k(v4, pf[0], o[6], 0, 0, 0);
          o[6] = __builtin_amdgcn_mfma_f32_16x16x16bf16_1k(v5, pf[1], o[6], 0, 0, 0);
          o[7] = __builtin_amdgcn_mfma_f32_16x16x16bf16_1k(v6, pf[0], o[7], 0, 0, 0);
          o[7] = __builtin_amdgcn_mfma_f32_16x16x16bf16_1k(v7, pf[1], o[7], 0, 0, 0);
          __builtin_amdgcn_s_setprio(0);
        }
      }
      __builtin_amdgcn_sched_barrier(0);
      __builtin_amdgcn_s_barrier();
    }
  }
#undef LDK
#undef LDV
  ushort_t* ob = Opart + (size_t)s * 4194304 + ((size_t)(b * 1024 + qt * 16 + r) * 16 + h) * 128;
#pragma unroll
  for (int dblk = 0; dblk < 8; ++dblk) {
    u16x4 ov;
#pragma unroll
    for (int tt = 0; tt < 4; ++tt) ov[tt] = f2bf(o[dblk][tt]);
    *(u16x4*)(ob + dblk * 16 + g * 4) = ov;
  }
  if (g == 0) {
    float2 ml; ml.x = m_run; ml.y = l_run;
    Ml[((size_t)(s * 2 + b) * 1024 + qt * 16 + r) * 16 + h] = ml;
  }
}

// ---------- combine 2 split partials (bf16, log2-domain m) + RMS norm + accumulate ----------
template <int FIRST>
__global__ __launch_bounds__(256) void rms_combine(const ushort_t* __restrict__ Opart, const float2* __restrict__ Ml,
                                                   const float* __restrict__ lnw, const float* __restrict__ lam,
                                                   int li, float* __restrict__ total) {
  int row = blockIdx.x;
  int t8 = threadIdx.x * 8;
  int h = t8 >> 7;
  float2 ml0 = Ml[(size_t)row * 16 + h];
  float2 ml1 = Ml[(size_t)(row + 2048) * 16 + h];
  float M = fmaxf(ml0.x, ml1.x);
  float w0 = exp2f(ml0.x - M), w1 = exp2f(ml1.x - M);
  float rinv = 1.f / (w0 * ml0.y + w1 * ml1.y);
  w0 *= rinv; w1 *= rinv;
  const ushort_t* a0 = Opart + (size_t)row * 2048 + t8;
  const ushort_t* a1 = a0 + 4194304;
  u16x4 p00 = *(const u16x4*)(a0);
  u16x4 p01 = *(const u16x4*)(a0 + 4);
  u16x4 p10 = *(const u16x4*)(a1);
  u16x4 p11 = *(const u16x4*)(a1 + 4);
  f32x4 v0, v1;
#pragma unroll
  for (int k = 0; k < 4; ++k) {
    v0[k] = w0 * bf2f(p00[k]) + w1 * bf2f(p10[k]);
    v1[k] = w0 * bf2f(p01[k]) + w1 * bf2f(p11[k]);
  }
  float ss = v0.x * v0.x + v0.y * v0.y + v0.z * v0.z + v0.w * v0.w +
             v1.x * v1.x + v1.y * v1.y + v1.z * v1.z + v1.w * v1.w;
#pragma unroll
  for (int m = 1; m < 64; m <<= 1) ss += __shfl_xor(ss, m, 64);
  __shared__ float red[4];
  int w = threadIdx.x >> 6, lane = threadIdx.x & 63;
  if (lane == 0) red[w] = ss;
  __syncthreads();
  ss = red[0] + red[1] + red[2] + red[3];
  float sca = rsqrtf(ss * (1.f / 2048.f) + 1e-5f) * lam[li];
  f32x4 w0v = *(const f32x4*)(lnw + t8);
  f32x4 w1v = *(const f32x4*)(lnw + t8 + 4);
  float* o = total + (size_t)row * 2048 + t8;
  f32x4 r0, r1;
#pragma unroll
  for (int k = 0; k < 4; ++k) { r0[k] = v0[k] * sca * w0v[k]; r1[k] = v1[k] * sca * w1v[k]; }
  if (!FIRST) {
    f32x4 q0 = *(const f32x4*)(o);
    f32x4 q1 = *(const f32x4*)(o + 4);
#pragma unroll
    for (int k = 0; k < 4; ++k) { r0[k] += q0[k]; r1[k] += q1[k]; }
  }
  *(f32x4*)(o) = r0;
  *(f32x4*)(o + 4) = r1;
}

// ---------- final: y = rms(total + alpha*x)*flw -> bf16 ----------
__global__ __launch_bounds__(256) void final_norm(const float* __restrict__ total, const float* __restrict__ x,
                                                  const float* __restrict__ alphap, const float* __restrict__ flw,
                                                  ushort_t* __restrict__ ybf) {
  int row = blockIdx.x;
  float al = alphap[0];
  int t8 = threadIdx.x * 8;
  const float* tp = total + (size_t)row * 2048 + t8;
  const float* xp = x + (size_t)row * 2048 + t8;
  f32x4 t0 = *(const f32x4*)(tp);
  f32x4 t1 = *(const f32x4*)(tp + 4);
  f32x4 x0 = *(const f32x4*)(xp);
  f32x4 x1 = *(const f32x4*)(xp + 4);
  float y[8];
#pragma unroll
  for (int k = 0; k < 4; ++k) { y[k] = t0[k] + al * x0[k]; y[4 + k] = t1[k] + al * x1[k]; }
  float ss = 0.f;
#pragma unroll
  for (int k = 0; k < 8; ++k) ss += y[k] * y[k];
#pragma unroll
  for (int m = 1; m < 64; m <<= 1) ss += __shfl_xor(ss, m, 64);
  __shared__ float red[4];
  int w = threadIdx.x >> 6, lane = threadIdx.x & 63;
  if (lane == 0) red[w] = ss;
  __syncthreads();
  ss = red[0] + red[1] + red[2] + red[3];
  float s = rsqrtf(ss * (1.f / 2048.f) + 1e-5f);
  f32x4 w0 = *(const f32x4*)(flw + t8);
  f32x4 w1 = *(const f32x4*)(flw + t8 + 4);
  u16x4 o0, o1;
#pragma unroll
  for (int k = 0; k < 4; ++k) {
    o0[k] = f2bf(y[k] * s * w0[k]);
    o1[k] = f2bf(y[4 + k] * s * w1[k]);
  }
  *(u16x4*)(ybf + (size_t)row * 2048 + t8) = o0;
  *(u16x4*)(ybf + (size_t)row * 2048 + t8 + 4) = o1;
}

// ---------- host ----------
extern "C" void kernel_launch(void* const* d_in, const int* in_sizes, int n_in,
                              void* d_out, int out_size, void* d_ws, size_t ws_size,
                              hipStream_t stream) {
  const float* x = (const float*)d_in[0];
  const float* cosT = (const float*)d_in[1];
  const float* sinT = (const float*)d_in[2];
  const float* wq = (const float*)d_in[3];
  const float* wk = (const float*)d_in[4];
  const float* wv = (const float*)d_in[5];
  const float* lnw = (const float*)d_in[6];
  const float* lambdas = (const float*)d_in[7];
  const float* w_out = (const float*)d_in[8];
  const float* flw = (const float*)d_in[9];
  const float* alpha = (const float*)d_in[10];

  const size_t ME = 4194304ull;
  char* p = (char*)d_ws;
  size_t off = 0;
  auto alc = [&](size_t bytes) -> void* {
    void* r = p + off;
    off += (bytes + 255) & ~(size_t)255;
    return r;
  };
  ushort_t* xb = (ushort_t*)alc(ME * 2);
  void* uni = alc(2 * ME * 4);                // 32 MB union: wl(24) / Opart-bf16(16) / Ppart(32)
  ushort_t* wl = (ushort_t*)uni;
  ushort_t* Opart = (ushort_t*)uni;
  float* Ppart = (float*)uni;
  ushort_t* q = (ushort_t*)alc(ME * 2);
  ushort_t* K0 = (ushort_t*)alc(ME * 2);
  ushort_t* K1 = (ushort_t*)alc(2 * ME * 2);
  ushort_t* K2 = (ushort_t*)alc(4 * ME * 2);
  ushort_t* V0 = (ushort_t*)alc(ME * 2);
  ushort_t* V1 = (ushort_t*)alc(2 * ME * 2);
  ushort_t* V2 = (ushort_t*)alc(4 * ME * 2);
  float* total = (float*)alc(ME * 4);
  float2* Ml = (float2*)alc(65536 * 8);
  float* lam = (float*)alc(256);
  ushort_t* ybf = q;
  ushort_t* wob = K0;

  f2b_kernel<<<4096, 256, 0, stream>>>(x, xb, 4194304);
  lam_kernel<<<1, 64, 0, stream>>>(lambdas, lam);

  ushort_t* Kc[3] = {K0, K1, K2};
  ushort_t* Vc[3] = {V0, V1, V2};

  for (int li = 0; li < 3; ++li) {
    int L = 1024 << li;
    size_t woff = (size_t)li * ME;
    f2b3_kernel<<<12288, 256, 0, stream>>>(wq + woff, wk + woff, wv + woff, wl);
    gemm_qkv256<<<192, 512, 0, stream>>>(xb, wl, wl + ME, wl + 2 * ME,
                                         q, Kc[li], Vc[li], L);
    rope_k<<<2048, 256, 0, stream>>>(Kc[li], cosT, sinT, L);
    if (li == 1)
      layer1_cache<<<4096, 256, 0, stream>>>(K0, K1, K2, V0, V1, cosT, sinT);
    else if (li == 2)
      layer2_cache<<<10240, 256, 0, stream>>>(K1, K2, V1, V2, cosT, sinT);
    attn_kernel<<<1024, 256, 0, stream>>>(q, Kc[li], Vc[li], cosT, sinT, Opart, Ml, L);
    if (li == 0)
      rms_combine<1><<<2048, 256, 0, stream>>>(Opart, Ml, lnw, lam, 0, total);
    else
      rms_combine<0><<<2048, 256, 0, stream>>>(Opart, Ml, lnw + (size_t)li * 2048, lam, li, total);
  }

  f2b_kernel<<<4096, 256, 0, stream>>>(w_out, wob, 4194304);
  final_norm<<<2048, 256, 0, stream>>>(total, x, alpha, flw, ybf);
  gemm_bt_part<<<dim3(16, 16, 2), 256, 0, stream>>>(ybf, wob, Ppart);
  add2_kernel<<<4096, 256, 0, stream>>>(Ppart, Ppart + ME, (float*)d_out);
}